// Round 6
// baseline (884.685 us; speedup 1.0000x reference)
//
#include <hip/hip_runtime.h>
#include <cmath>

#define NB 512
#define NT 200
#define NIN 88
#define NH 60
#define NZ 100

__device__ __forceinline__ float fast_tanh(float x) {
    float cx = fminf(fmaxf(x, -10.f), 10.f);
    float e  = __expf(2.f * cx);
    return (e - 1.f) * __builtin_amdgcn_rcpf(e + 1.f);
}
__device__ __forceinline__ float fast_softplus(float x) {
    return fmaxf(x, 0.f) + __logf(1.f + __expf(-fabsf(x)));
}

// Barrier without the vmcnt(0) drain __syncthreads() emits; LDS (lgkm)
// ordering only. Global loads/stores ride across, waited at their use.
__device__ __forceinline__ void block_sync_lds() {
    asm volatile("s_waitcnt lgkmcnt(0)" ::: "memory");
    __builtin_amdgcn_s_barrier();
    asm volatile("" ::: "memory");
}

// ---------------------------------------------------------------------------
// Kernel 1: pre[b][t][h] = x_rev[b][t] . W_ih[h] + b_ih[h] + b_hh[h]
// Fully parallel; input projection off the serial critical path.
// ---------------------------------------------------------------------------
__global__ __launch_bounds__(256, 1)
void pre_kernel(const float* __restrict__ xrev, const float* __restrict__ W_ih,
                const float* __restrict__ b_ih, const float* __restrict__ b_hh,
                float* __restrict__ pre)
{
    const int b = blockIdx.x;
    const float* xb = xrev + (size_t)b * NT * NIN;
    float* pb = pre + (size_t)b * NT * NH;
    for (int i = threadIdx.x; i < NT * NH; i += 256) {
        const int t = i / NH, h = i - t * NH;
        const float4* xr = reinterpret_cast<const float4*>(xb + (size_t)t * NIN);
        const float4* wr = reinterpret_cast<const float4*>(W_ih + h * NIN);
        float a0 = 0.f, a1 = 0.f, a2 = 0.f, a3 = 0.f;
        float c0 = 0.f, c1 = 0.f, c2 = 0.f, c3 = 0.f;
#pragma unroll
        for (int k = 0; k < 11; ++k) {
            float4 x = xr[k], w = wr[k];
            a0 += x.x * w.x; a1 += x.y * w.y; a2 += x.z * w.z; a3 += x.w * w.w;
        }
#pragma unroll
        for (int k = 11; k < 22; ++k) {
            float4 x = xr[k], w = wr[k];
            c0 += x.x * w.x; c1 += x.y * w.y; c2 += x.z * w.z; c3 += x.w * w.w;
        }
        pb[i] = ((a0 + c0) + (a1 + c1)) + ((a2 + c2) + (a3 + c3)) + b_ih[h] + b_hh[h];
    }
}

// ---------------------------------------------------------------------------
// Kernel 2: fused RNN + combiner. One block per sequence, 320 threads = 5
// waves, LDS h_rev (48 KB) -> 2 blocks/CU, all 512 blocks co-resident.
// Phase A: wave0 serial recurrence h = relu(pre[t] + h@W_hh.T), h_rev scatter
//          in LDS (no global stores); waves1-4 park at the phase barrier
//          having already loaded their phase-B weights.
// Phase B: wave0 lane<60: w[0:100]=W_zh row -> hcomb (reads h_rev from LDS);
//          waves1-4: pair p=(wv-1)*32+(lane>>1), even lane W_hl[p] / odd
//          W_hs[p] in w[0:60]; loc/sc exchanged via shfl_xor(1).
// ---------------------------------------------------------------------------
__global__ __launch_bounds__(320, 1)
void fused_kernel(const int*   __restrict__ seqlen, // [B]
                  const float* __restrict__ eps,    // [T][B][Z]
                  const float* __restrict__ W_hh,   // [H][H]
                  const float* __restrict__ h0,
                  const float* __restrict__ zq0,
                  const float* __restrict__ W_zh,   // [H][Z]
                  const float* __restrict__ b_zh,
                  const float* __restrict__ W_hl,   // [Z][H]
                  const float* __restrict__ b_hl,
                  const float* __restrict__ W_hs,   // [Z][H]
                  const float* __restrict__ b_hs,
                  const float* __restrict__ pre,    // [B][T][H] (ws)
                  float* __restrict__ out)          // 3 x [B][T][Z]
{
    __shared__ __align__(16) float h_rev[NT][NH];   // 48000 B
    __shared__ __align__(16) float hbuf[NH + 4];
    __shared__ __align__(16) float zbuf[NZ];
    __shared__ __align__(16) float hcomb[NH + 4];

    const int b    = blockIdx.x;
    const int tid  = threadIdx.x;
    const int wave = tid >> 6;
    const int lane = tid & 63;
    const int sl   = seqlen[b];

    // zero only the padded tail rows [sl, NT)
    {
        const int tail = (NT - sl) * NH;
        float* base = &h_rev[0][0] + sl * NH;
        for (int i = tid; i < tail; i += 320) base[i] = 0.0f;
    }

    float w[NZ];          // overlay: A-wave0 {W_hh row:0..60} -> B-wave0
                          // {W_zh row:0..100}; B-waves1-4 {W_hl|W_hs row:0..60}
    float bias = 0.f;
    const int  p      = (wave - 1) * 32 + (lane >> 1);
    const bool outln  = (wave > 0) && (p < NZ);
    const bool evenln = ((lane & 1) == 0);
    float e_cur = 0.f;

    if (wave == 0) {
        if (lane < NH) {
            const float4* q = reinterpret_cast<const float4*>(W_hh + lane * NH);
#pragma unroll
            for (int k = 0; k < NH / 4; ++k) {
                float4 v = q[k];
                w[4*k+0] = v.x; w[4*k+1] = v.y; w[4*k+2] = v.z; w[4*k+3] = v.w;
            }
            hbuf[lane] = h0[lane];
        }
    } else if (outln) {
        const float* row = evenln ? (W_hl + p * NH) : (W_hs + p * NH);
        const float4* q = reinterpret_cast<const float4*>(row);
#pragma unroll
        for (int k = 0; k < NH / 4; ++k) {
            float4 v = q[k];
            w[4*k+0] = v.x; w[4*k+1] = v.y; w[4*k+2] = v.z; w[4*k+3] = v.w;
        }
        bias = evenln ? b_hl[p] : b_hs[p];
        if (evenln) {
            zbuf[p] = zq0[p];
            e_cur   = eps[(size_t)b * NZ + p];       // eps[0][b][p]
        }
    }
    __syncthreads();   // h_rev tail zeroed; hbuf/zbuf init visible

    // ---------------- Phase A: serial RNN (wave0 only) ----------------
    if (wave == 0) {
        const float* pb = pre + (size_t)b * NT * NH;
        float pcur = (lane < NH) ? pb[lane] : 0.f;
        for (int t = 0; t < NT; ++t) {
            float pnxt = (t + 1 < NT && lane < NH) ? pb[(size_t)(t+1)*NH + lane] : 0.f;
            const float4* h4 = reinterpret_cast<const float4*>(hbuf);
            float a0 = pcur, a1 = 0.f, a2 = 0.f, a3 = 0.f;
#pragma unroll
            for (int k = 0; k < NH / 4; ++k) {
                float4 v = h4[k];
                a0 = fmaf(v.x, w[4*k+0], a0); a1 = fmaf(v.y, w[4*k+1], a1);
                a2 = fmaf(v.z, w[4*k+2], a2); a3 = fmaf(v.w, w[4*k+3], a3);
            }
            float hn = fmaxf((a0 + a1) + (a2 + a3), 0.f);
            if (lane < NH) {
                hbuf[lane] = hn;                 // single-wave in-order LDS
                if (t < sl) h_rev[sl - 1 - t][lane] = hn;
            }
            pcur = pnxt;
        }
        // overlay reload for phase B: W_zh row + bias
        if (lane < NH) {
            const float4* q = reinterpret_cast<const float4*>(W_zh + lane * NZ);
#pragma unroll
            for (int k = 0; k < NZ / 4; ++k) {
                float4 v = q[k];
                w[4*k+0] = v.x; w[4*k+1] = v.y; w[4*k+2] = v.z; w[4*k+3] = v.w;
            }
            bias = b_zh[lane];
        }
    }
    __syncthreads();   // h_rev complete; phase-B state ready

    // ---------------- Phase B: combiner ----------------
    float* out_z = out;
    float* out_l = out + (size_t)NB * NT * NZ;
    float* out_s = out + (size_t)2 * NB * NT * NZ;

    for (int t = 0; t < NT; ++t) {
        float e_nxt = 0.f;
        if (wave == 0) {
            float hr = (lane < NH) ? h_rev[t][lane] : 0.f;
            const float4* z4 = reinterpret_cast<const float4*>(zbuf);
            float a0=0.f,a1=0.f,a2=0.f,a3=0.f, c0=0.f,c1=0.f,c2=0.f,c3=0.f;
#pragma unroll
            for (int k = 0; k < 13; ++k) {
                float4 v = z4[k];
                a0 += v.x*w[4*k+0]; a1 += v.y*w[4*k+1];
                a2 += v.z*w[4*k+2]; a3 += v.w*w[4*k+3];
            }
#pragma unroll
            for (int k = 13; k < 25; ++k) {
                float4 v = z4[k];
                c0 += v.x*w[4*k+0]; c1 += v.y*w[4*k+1];
                c2 += v.z*w[4*k+2]; c3 += v.w*w[4*k+3];
            }
            if (lane < NH) {
                float a = ((a0+c0)+(a1+c1)) + ((a2+c2)+(a3+c3)) + bias;
                hcomb[lane] = 0.5f * (fast_tanh(a) + hr);
            }
        } else if (outln && evenln && t + 1 < NT) {
            e_nxt = eps[((size_t)(t + 1) * NB + b) * NZ + p];  // rides across
        }
        block_sync_lds();  // hcomb visible; wave0's zbuf reads complete

        if (outln) {
            const float4* h4 = reinterpret_cast<const float4*>(hcomb);
            float c0=0.f,c1=0.f,c2=0.f,c3=0.f, c4=0.f,c5=0.f,c6=0.f,c7=0.f;
#pragma unroll
            for (int k = 0; k < 8; ++k) {
                float4 v = h4[k];
                c0 += v.x*w[4*k+0]; c1 += v.y*w[4*k+1];
                c2 += v.z*w[4*k+2]; c3 += v.w*w[4*k+3];
            }
#pragma unroll
            for (int k = 8; k < 15; ++k) {
                float4 v = h4[k];
                c4 += v.x*w[4*k+0]; c5 += v.y*w[4*k+1];
                c6 += v.z*w[4*k+2]; c7 += v.w*w[4*k+3];
            }
            float s = ((c0+c4)+(c1+c5)) + ((c2+c6)+(c3+c7)) + bias;
            float res = evenln ? s : fast_softplus(s);   // even: loc, odd: sc
            float other = __shfl_xor(res, 1, 64);
            size_t oi = ((size_t)b * NT + t) * NZ + p;
            if (evenln) {
                float zv = res + other * e_cur;          // loc + sc*eps
                out_z[oi] = zv;
                out_l[oi] = res;
                zbuf[p]   = zv;
                e_cur     = e_nxt;
            } else {
                out_s[oi] = res;
            }
        }
        block_sync_lds();  // zbuf ready for next step
    }
}

// ---------------------------------------------------------------------------
// Fallback (ws too small): proven monolithic kernel (no workspace).
// ---------------------------------------------------------------------------
__global__ __launch_bounds__(128, 1)
void encoder_mono(const float* __restrict__ xrev, const int* __restrict__ seqlen,
                  const float* __restrict__ eps,
                  const float* __restrict__ W_ih, const float* __restrict__ W_hh,
                  const float* __restrict__ b_ih, const float* __restrict__ b_hh,
                  const float* __restrict__ h0,   const float* __restrict__ zq0,
                  const float* __restrict__ W_zh, const float* __restrict__ b_zh,
                  const float* __restrict__ W_hl, const float* __restrict__ b_hl,
                  const float* __restrict__ W_hs, const float* __restrict__ b_hs,
                  float* __restrict__ out)
{
    __shared__ __align__(16) float h_rev[NT][NH];
    __shared__ __align__(16) float xbuf[NIN];
    __shared__ __align__(16) float hbuf[NH];
    __shared__ __align__(16) float zbuf[NZ];
    __shared__ __align__(16) float hcomb[NH];

    const int b = blockIdx.x, tid = threadIdx.x;
    const int wave = tid >> 6, lane = tid & 63;
    const int sl = seqlen[b];

    for (int i = tid; i < NT * NH; i += 128) (&h_rev[0][0])[i] = 0.0f;
    __syncthreads();

    if (wave == 0) {
        float wih[NIN], whh[NH];
        float bias = 0.f;
        if (lane < NH) {
            const float4* pp = reinterpret_cast<const float4*>(W_ih + lane * NIN);
#pragma unroll
            for (int k = 0; k < NIN / 4; ++k) {
                float4 v = pp[k];
                wih[4*k+0]=v.x; wih[4*k+1]=v.y; wih[4*k+2]=v.z; wih[4*k+3]=v.w;
            }
            const float4* q = reinterpret_cast<const float4*>(W_hh + lane * NH);
#pragma unroll
            for (int k = 0; k < NH / 4; ++k) {
                float4 v = q[k];
                whh[4*k+0]=v.x; whh[4*k+1]=v.y; whh[4*k+2]=v.z; whh[4*k+3]=v.w;
            }
            bias = b_ih[lane] + b_hh[lane];
            hbuf[lane] = h0[lane];
        } else {
#pragma unroll
            for (int k = 0; k < NIN; ++k) wih[k] = 0.f;
#pragma unroll
            for (int k = 0; k < NH; ++k) whh[k] = 0.f;
        }
        const float* xb = xrev + (size_t)b * NT * NIN;
        float xa = xb[lane];
        float xc = (lane < NIN - 64) ? xb[64 + lane] : 0.f;
        for (int t = 0; t < NT; ++t) {
            xbuf[lane] = xa;
            if (lane < NIN - 64) xbuf[64 + lane] = xc;
            if (t + 1 < NT) {
                xa = xb[(size_t)(t+1)*NIN + lane];
                xc = (lane < NIN - 64) ? xb[(size_t)(t+1)*NIN + 64 + lane] : 0.f;
            }
            float a0=0.f,a1=0.f,a2=0.f,a3=0.f;
            const float4* x4 = reinterpret_cast<const float4*>(xbuf);
#pragma unroll
            for (int k = 0; k < NIN / 4; ++k) {
                float4 v = x4[k];
                a0 += v.x*wih[4*k+0]; a1 += v.y*wih[4*k+1];
                a2 += v.z*wih[4*k+2]; a3 += v.w*wih[4*k+3];
            }
            const float4* h4 = reinterpret_cast<const float4*>(hbuf);
#pragma unroll
            for (int k = 0; k < NH / 4; ++k) {
                float4 v = h4[k];
                a0 += v.x*whh[4*k+0]; a1 += v.y*whh[4*k+1];
                a2 += v.z*whh[4*k+2]; a3 += v.w*whh[4*k+3];
            }
            float hn = fmaxf((a0+a1)+(a2+a3)+bias, 0.f);
            if (lane < NH) {
                hbuf[lane] = hn;
                if (t < sl) h_rev[sl-1-t][lane] = hn;
            }
        }
    }
    __syncthreads();

    const int o = 50 * wave + lane;
    float wzr[NZ]; float bz = 0.f;
    if (wave == 0 && lane < NH) {
        const float4* pp = reinterpret_cast<const float4*>(W_zh + lane * NZ);
#pragma unroll
        for (int k = 0; k < NZ / 4; ++k) {
            float4 v = pp[k];
            wzr[4*k+0]=v.x; wzr[4*k+1]=v.y; wzr[4*k+2]=v.z; wzr[4*k+3]=v.w;
        }
        bz = b_zh[lane];
    } else {
#pragma unroll
        for (int k = 0; k < NZ; ++k) wzr[k] = 0.f;
    }
    float wl[NH], ws_[NH]; float bl = 0.f, bs = 0.f;
    if (lane < 50) {
        const float4* pp = reinterpret_cast<const float4*>(W_hl + o * NH);
        const float4* q  = reinterpret_cast<const float4*>(W_hs + o * NH);
#pragma unroll
        for (int k = 0; k < NH / 4; ++k) {
            float4 v = pp[k];
            wl[4*k+0]=v.x; wl[4*k+1]=v.y; wl[4*k+2]=v.z; wl[4*k+3]=v.w;
            float4 u = q[k];
            ws_[4*k+0]=u.x; ws_[4*k+1]=u.y; ws_[4*k+2]=u.z; ws_[4*k+3]=u.w;
        }
        bl = b_hl[o]; bs = b_hs[o];
        zbuf[o] = zq0[o];
    } else {
#pragma unroll
        for (int k = 0; k < NH; ++k) { wl[k]=0.f; ws_[k]=0.f; }
    }
    __syncthreads();

    float* out_z = out;
    float* out_l = out + (size_t)NB * NT * NZ;
    float* out_s = out + (size_t)2 * NB * NT * NZ;
    const float* epsb = eps + (size_t)b * NZ;
    float e_cur = (lane < 50) ? epsb[o] : 0.f;

    for (int t = 0; t < NT; ++t) {
        if (wave == 0) {
            float a0=0.f,a1=0.f,a2=0.f,a3=0.f;
            const float4* z4 = reinterpret_cast<const float4*>(zbuf);
#pragma unroll
            for (int k = 0; k < NZ / 4; ++k) {
                float4 v = z4[k];
                a0 += v.x*wzr[4*k+0]; a1 += v.y*wzr[4*k+1];
                a2 += v.z*wzr[4*k+2]; a3 += v.w*wzr[4*k+3];
            }
            if (lane < NH) {
                float a = (a0+a1)+(a2+a3)+bz;
                hcomb[lane] = 0.5f * (fast_tanh(a) + h_rev[t][lane]);
            }
        }
        block_sync_lds();
        float e_nxt = 0.f;
        if (t + 1 < NT && lane < 50) e_nxt = epsb[(size_t)(t+1)*NB*NZ + o];
        if (lane < 50) {
            float c0=0.f,c1=0.f,c2=0.f,c3=0.f, d0=0.f,d1=0.f,d2=0.f,d3=0.f;
            const float4* h4 = reinterpret_cast<const float4*>(hcomb);
#pragma unroll
            for (int k = 0; k < NH / 4; ++k) {
                float4 v = h4[k];
                c0 += v.x*wl[4*k+0];  c1 += v.y*wl[4*k+1];
                c2 += v.z*wl[4*k+2];  c3 += v.w*wl[4*k+3];
                d0 += v.x*ws_[4*k+0]; d1 += v.y*ws_[4*k+1];
                d2 += v.z*ws_[4*k+2]; d3 += v.w*ws_[4*k+3];
            }
            float loc = (c0+c1)+(c2+c3)+bl;
            float ps  = (d0+d1)+(d2+d3)+bs;
            float sc  = fast_softplus(ps);
            float zv  = loc + sc * e_cur;
            size_t oi = ((size_t)b * NT + t) * NZ + o;
            out_z[oi]=zv; out_l[oi]=loc; out_s[oi]=sc;
            zbuf[o]=zv;
        }
        e_cur = e_nxt;
        block_sync_lds();
    }
}

extern "C" void kernel_launch(void* const* d_in, const int* in_sizes, int n_in,
                              void* d_out, int out_size, void* d_ws, size_t ws_size,
                              hipStream_t stream) {
    const float* xrev   = (const float*)d_in[1];
    const int*   seqlen = (const int*)  d_in[3];
    const float* eps    = (const float*)d_in[4];
    const float* W_ih   = (const float*)d_in[5];
    const float* W_hh   = (const float*)d_in[6];
    const float* b_ih   = (const float*)d_in[7];
    const float* b_hh   = (const float*)d_in[8];
    const float* h0     = (const float*)d_in[9];
    const float* zq0    = (const float*)d_in[10];
    const float* W_zh   = (const float*)d_in[11];
    const float* b_zh   = (const float*)d_in[12];
    const float* W_hl   = (const float*)d_in[13];
    const float* b_hl   = (const float*)d_in[14];
    const float* W_hs   = (const float*)d_in[15];
    const float* b_hs   = (const float*)d_in[16];
    float* out = (float*)d_out;

    const size_t pre_bytes = (size_t)NB * NT * NH * sizeof(float);
    if (ws_size >= pre_bytes) {
        float* pre = (float*)d_ws;
        pre_kernel<<<NB, 256, 0, stream>>>(xrev, W_ih, b_ih, b_hh, pre);
        fused_kernel<<<NB, 320, 0, stream>>>(seqlen, eps, W_hh, h0, zq0,
                                             W_zh, b_zh, W_hl, b_hl, W_hs, b_hs,
                                             pre, out);
    } else {
        encoder_mono<<<NB, 128, 0, stream>>>(xrev, seqlen, eps,
                                             W_ih, W_hh, b_ih, b_hh, h0, zq0,
                                             W_zh, b_zh, W_hl, b_hl, W_hs, b_hs,
                                             out);
    }
}

// Round 7
// 515.127 us; speedup vs baseline: 1.7174x; 1.7174x over previous
//
#include <hip/hip_runtime.h>
#include <cmath>

#define NB 512
#define NT 200
#define NIN 88
#define NH 60
#define NZ 100

__device__ __forceinline__ float fast_tanh(float x) {
    float cx = fminf(fmaxf(x, -10.f), 10.f);
    float e  = __expf(2.f * cx);
    return (e - 1.f) * __builtin_amdgcn_rcpf(e + 1.f);
}
__device__ __forceinline__ float fast_softplus(float x) {
    return fmaxf(x, 0.f) + __logf(1.f + __expf(-fabsf(x)));
}
// LDS-only barrier (no vmcnt drain); global ops ride across, waited at use.
__device__ __forceinline__ void block_sync_lds() {
    asm volatile("s_waitcnt lgkmcnt(0)" ::: "memory");
    __builtin_amdgcn_s_barrier();
    asm volatile("" ::: "memory");
}

// ---------------------------------------------------------------------------
// Kernel 1: pre[b][t][h] = x_rev[b][t].W_ih[h] + b_ih[h] + b_hh[h]  (parallel)
// ---------------------------------------------------------------------------
__global__ __launch_bounds__(256, 1)
void pre_kernel(const float* __restrict__ xrev, const float* __restrict__ W_ih,
                const float* __restrict__ b_ih, const float* __restrict__ b_hh,
                float* __restrict__ pre)
{
    const int b = blockIdx.x;
    const float* xb = xrev + (size_t)b * NT * NIN;
    float* pb = pre + (size_t)b * NT * NH;
    for (int i = threadIdx.x; i < NT * NH; i += 256) {
        const int t = i / NH, h = i - t * NH;
        const float4* xr = reinterpret_cast<const float4*>(xb + (size_t)t * NIN);
        const float4* wr = reinterpret_cast<const float4*>(W_ih + h * NIN);
        float a0 = 0.f, a1 = 0.f, a2 = 0.f, a3 = 0.f;
        float c0 = 0.f, c1 = 0.f, c2 = 0.f, c3 = 0.f;
#pragma unroll
        for (int k = 0; k < 11; ++k) {
            float4 x = xr[k], w = wr[k];
            a0 += x.x * w.x; a1 += x.y * w.y; a2 += x.z * w.z; a3 += x.w * w.w;
        }
#pragma unroll
        for (int k = 11; k < 22; ++k) {
            float4 x = xr[k], w = wr[k];
            c0 += x.x * w.x; c1 += x.y * w.y; c2 += x.z * w.z; c3 += x.w * w.w;
        }
        pb[i] = ((a0 + c0) + (a1 + c1)) + ((a2 + c2) + (a3 + c3)) + b_ih[h] + b_hh[h];
    }
}

// ---------------------------------------------------------------------------
// Kernel 2: fused encoder. 128 threads = 2 waves per block (the shape proven
// to co-schedule 2 blocks/CU -> all 512 blocks resident in ONE round).
// Phase A: wave0 serial recurrence via pre (60 FMA/step, intra-wave LDS hbuf,
//          no barriers); h_rev scattered in LDS.
// Phase B: ONE barrier/step. Each wave redundantly computes z-dot->hcomb
//          (lane<60 holds a W_zh row; hcomb exchanged via per-wave LDS, no
//          barrier). Lane l<50 of wave w owns output o=50w+l (120 weight
//          regs). zbuf double-buffered: read zb[t&1], write zb[t&1^1].
// ---------------------------------------------------------------------------
__global__ __launch_bounds__(128, 1)
void fused128(const int*   __restrict__ seqlen, // [B]
              const float* __restrict__ eps,    // [T][B][Z]
              const float* __restrict__ W_hh,   // [H][H]
              const float* __restrict__ h0,
              const float* __restrict__ zq0,
              const float* __restrict__ W_zh,   // [H][Z]
              const float* __restrict__ b_zh,
              const float* __restrict__ W_hl,   // [Z][H]
              const float* __restrict__ b_hl,
              const float* __restrict__ W_hs,   // [Z][H]
              const float* __restrict__ b_hs,
              const float* __restrict__ pre,    // [B][T][H] (ws)
              float* __restrict__ out)          // 3 x [B][T][Z]
{
    __shared__ __align__(16) float h_rev[NT][NH];     // 48000 B
    __shared__ __align__(16) float hbuf[NH + 4];
    __shared__ __align__(16) float zb[2][NZ + 4];     // double-buffered z
    __shared__ __align__(16) float hcw[2][NH + 4];    // per-wave hcomb

    const int b    = blockIdx.x;
    const int tid  = threadIdx.x;
    const int wv   = tid >> 6;
    const int lane = tid & 63;
    const int sl   = seqlen[b];

    // zero only the padded tail rows [sl, NT)
    {
        const int tail = (NT - sl) * NH;
        float* base = &h_rev[0][0] + sl * NH;
        for (int i = tid; i < tail; i += 128) base[i] = 0.0f;
    }

    float wzh[NZ];    // wave0 phase A: [0:60]=W_hh row; phase B: W_zh row
    float wls[120];   // lane<50: [0:60]=W_hl[o], [60:120]=W_hs[o]
    float bz = 0.f, bl = 0.f, bs = 0.f;
    const int  o   = 50 * wv + lane;      // valid when lane<50
    const bool oln = (lane < 50);
    float e_cur = 0.f;

    // ---- prologue: per-role loads ----
    if (oln) {
        const float4* p = reinterpret_cast<const float4*>(W_hl + o * NH);
        const float4* q = reinterpret_cast<const float4*>(W_hs + o * NH);
#pragma unroll
        for (int k = 0; k < 15; ++k) {
            float4 v = p[k];
            wls[4*k+0]  = v.x; wls[4*k+1]  = v.y; wls[4*k+2]  = v.z; wls[4*k+3]  = v.w;
            float4 u = q[k];
            wls[60+4*k] = u.x; wls[61+4*k] = u.y; wls[62+4*k] = u.z; wls[63+4*k] = u.w;
        }
        bl = b_hl[o];
        bs = b_hs[o];
        e_cur = eps[(size_t)b * NZ + o];          // eps[0][b][o]
        zb[0][o] = zq0[o];
    } else {
#pragma unroll
        for (int k = 0; k < 120; ++k) wls[k] = 0.f;
    }

    if (wv == 0) {
        if (lane < NH) {
            const float4* q = reinterpret_cast<const float4*>(W_hh + lane * NH);
#pragma unroll
            for (int k = 0; k < 15; ++k) {
                float4 v = q[k];
                wzh[4*k+0] = v.x; wzh[4*k+1] = v.y; wzh[4*k+2] = v.z; wzh[4*k+3] = v.w;
            }
#pragma unroll
            for (int k = 60; k < NZ; ++k) wzh[k] = 0.f;
            hbuf[lane] = h0[lane];
        } else {
#pragma unroll
            for (int k = 0; k < NZ; ++k) wzh[k] = 0.f;
        }
    } else {
        if (lane < NH) {
            const float4* q = reinterpret_cast<const float4*>(W_zh + lane * NZ);
#pragma unroll
            for (int k = 0; k < 25; ++k) {
                float4 v = q[k];
                wzh[4*k+0] = v.x; wzh[4*k+1] = v.y; wzh[4*k+2] = v.z; wzh[4*k+3] = v.w;
            }
            bz = b_zh[lane];
        } else {
#pragma unroll
            for (int k = 0; k < NZ; ++k) wzh[k] = 0.f;
        }
    }
    __syncthreads();   // h_rev tail + zb[0] + hbuf init visible

    // ---------------- Phase A: serial RNN (wave0 only, no barriers) ---------
    if (wv == 0) {
        const float* pb = pre + (size_t)b * NT * NH;
        float pcur = (lane < NH) ? pb[lane] : 0.f;
        for (int t = 0; t < NT; ++t) {
            float pnxt = (t + 1 < NT && lane < NH) ? pb[(size_t)(t+1)*NH + lane] : 0.f;
            const float4* h4 = reinterpret_cast<const float4*>(hbuf);
            float a0 = pcur, a1 = 0.f, a2 = 0.f, a3 = 0.f;
#pragma unroll
            for (int k = 0; k < 15; ++k) {
                float4 v = h4[k];
                a0 = fmaf(v.x, wzh[4*k+0], a0); a1 = fmaf(v.y, wzh[4*k+1], a1);
                a2 = fmaf(v.z, wzh[4*k+2], a2); a3 = fmaf(v.w, wzh[4*k+3], a3);
            }
            float hn = fmaxf((a0 + a1) + (a2 + a3), 0.f);
            if (lane < NH) {
                hbuf[lane] = hn;                  // single-wave in-order LDS
                if (t < sl) h_rev[sl - 1 - t][lane] = hn;
            }
            pcur = pnxt;
        }
        // overlay reload: W_zh row for phase B
        if (lane < NH) {
            const float4* q = reinterpret_cast<const float4*>(W_zh + lane * NZ);
#pragma unroll
            for (int k = 0; k < 25; ++k) {
                float4 v = q[k];
                wzh[4*k+0] = v.x; wzh[4*k+1] = v.y; wzh[4*k+2] = v.z; wzh[4*k+3] = v.w;
            }
            bz = b_zh[lane];
        } else {
#pragma unroll
            for (int k = 0; k < NZ; ++k) wzh[k] = 0.f;
        }
    }
    block_sync_lds();   // h_rev complete, zb[0] ready

    // ---------------- Phase B: combiner, 1 barrier/step ----------------
    float* out_z = out;
    float* out_l = out + (size_t)NB * NT * NZ;
    float* out_s = out + (size_t)2 * NB * NT * NZ;

    for (int t = 0; t < NT; ++t) {
        const int r = t & 1;

        // h_rev row for this step (LDS, independent of z-dot -> overlaps)
        float hrow = (lane < NH) ? h_rev[t][lane] : 0.f;

        // z-dot: zb[r] broadcast reads x W_zh row (both waves, redundant)
        const float4* z4 = reinterpret_cast<const float4*>(zb[r]);
        float a0=0.f,a1=0.f,a2=0.f,a3=0.f, c0=0.f,c1=0.f,c2=0.f,c3=0.f;
#pragma unroll
        for (int k = 0; k < 13; ++k) {
            float4 v = z4[k];
            a0 += v.x*wzh[4*k+0]; a1 += v.y*wzh[4*k+1];
            a2 += v.z*wzh[4*k+2]; a3 += v.w*wzh[4*k+3];
        }
#pragma unroll
        for (int k = 13; k < 25; ++k) {
            float4 v = z4[k];
            c0 += v.x*wzh[4*k+0]; c1 += v.y*wzh[4*k+1];
            c2 += v.z*wzh[4*k+2]; c3 += v.w*wzh[4*k+3];
        }

        // eps prefetch for next step (rides across the barrier)
        float e_nxt = (oln && t + 1 < NT)
                      ? eps[((size_t)(t + 1) * NB + b) * NZ + o] : 0.f;

        if (lane < NH) {
            float a = ((a0+c0)+(a1+c1)) + ((a2+c2)+(a3+c3)) + bz;
            hcw[wv][lane] = 0.5f * (fast_tanh(a) + hrow);
        }

        // intra-wave read-back of this wave's hcomb (in-order, no barrier)
        const float4* h4 = reinterpret_cast<const float4*>(hcw[wv]);
        float l0=0.f,l1=0.f,l2=0.f,l3=0.f, s0=0.f,s1=0.f,s2=0.f,s3=0.f;
#pragma unroll
        for (int k = 0; k < 15; ++k) {
            float4 v = h4[k];
            l0 += v.x*wls[4*k+0];  l1 += v.y*wls[4*k+1];
            l2 += v.z*wls[4*k+2];  l3 += v.w*wls[4*k+3];
            s0 += v.x*wls[60+4*k]; s1 += v.y*wls[61+4*k];
            s2 += v.z*wls[62+4*k]; s3 += v.w*wls[63+4*k];
        }
        if (oln) {
            float loc = (l0+l1) + (l2+l3) + bl;
            float ps  = (s0+s1) + (s2+s3) + bs;
            float sc  = fast_softplus(ps);
            float zv  = loc + sc * e_cur;
            size_t oi = ((size_t)b * NT + t) * NZ + o;
            out_z[oi] = zv;
            out_l[oi] = loc;
            out_s[oi] = sc;
            zb[r ^ 1][o] = zv;        // write the OTHER buffer (race-free)
            e_cur = e_nxt;
        }
        block_sync_lds();             // zb[r^1] visible; zb[r] reads done
    }
}

// ---------------------------------------------------------------------------
// Fallback (ws too small): proven monolithic kernel (no workspace).
// ---------------------------------------------------------------------------
__global__ __launch_bounds__(128, 1)
void encoder_mono(const float* __restrict__ xrev, const int* __restrict__ seqlen,
                  const float* __restrict__ eps,
                  const float* __restrict__ W_ih, const float* __restrict__ W_hh,
                  const float* __restrict__ b_ih, const float* __restrict__ b_hh,
                  const float* __restrict__ h0,   const float* __restrict__ zq0,
                  const float* __restrict__ W_zh, const float* __restrict__ b_zh,
                  const float* __restrict__ W_hl, const float* __restrict__ b_hl,
                  const float* __restrict__ W_hs, const float* __restrict__ b_hs,
                  float* __restrict__ out)
{
    __shared__ __align__(16) float h_rev[NT][NH];
    __shared__ __align__(16) float xbuf[NIN];
    __shared__ __align__(16) float hbuf[NH];
    __shared__ __align__(16) float zbuf[NZ];
    __shared__ __align__(16) float hcomb[NH];

    const int b = blockIdx.x, tid = threadIdx.x;
    const int wave = tid >> 6, lane = tid & 63;
    const int sl = seqlen[b];

    for (int i = tid; i < NT * NH; i += 128) (&h_rev[0][0])[i] = 0.0f;
    __syncthreads();

    if (wave == 0) {
        float wih[NIN], whh[NH];
        float bias = 0.f;
        if (lane < NH) {
            const float4* pp = reinterpret_cast<const float4*>(W_ih + lane * NIN);
#pragma unroll
            for (int k = 0; k < NIN / 4; ++k) {
                float4 v = pp[k];
                wih[4*k+0]=v.x; wih[4*k+1]=v.y; wih[4*k+2]=v.z; wih[4*k+3]=v.w;
            }
            const float4* q = reinterpret_cast<const float4*>(W_hh + lane * NH);
#pragma unroll
            for (int k = 0; k < NH / 4; ++k) {
                float4 v = q[k];
                whh[4*k+0]=v.x; whh[4*k+1]=v.y; whh[4*k+2]=v.z; whh[4*k+3]=v.w;
            }
            bias = b_ih[lane] + b_hh[lane];
            hbuf[lane] = h0[lane];
        } else {
#pragma unroll
            for (int k = 0; k < NIN; ++k) wih[k] = 0.f;
#pragma unroll
            for (int k = 0; k < NH; ++k) whh[k] = 0.f;
        }
        const float* xb = xrev + (size_t)b * NT * NIN;
        float xa = xb[lane];
        float xc = (lane < NIN - 64) ? xb[64 + lane] : 0.f;
        for (int t = 0; t < NT; ++t) {
            xbuf[lane] = xa;
            if (lane < NIN - 64) xbuf[64 + lane] = xc;
            if (t + 1 < NT) {
                xa = xb[(size_t)(t+1)*NIN + lane];
                xc = (lane < NIN - 64) ? xb[(size_t)(t+1)*NIN + 64 + lane] : 0.f;
            }
            float a0=0.f,a1=0.f,a2=0.f,a3=0.f;
            const float4* x4 = reinterpret_cast<const float4*>(xbuf);
#pragma unroll
            for (int k = 0; k < NIN / 4; ++k) {
                float4 v = x4[k];
                a0 += v.x*wih[4*k+0]; a1 += v.y*wih[4*k+1];
                a2 += v.z*wih[4*k+2]; a3 += v.w*wih[4*k+3];
            }
            const float4* h4 = reinterpret_cast<const float4*>(hbuf);
#pragma unroll
            for (int k = 0; k < NH / 4; ++k) {
                float4 v = h4[k];
                a0 += v.x*whh[4*k+0]; a1 += v.y*whh[4*k+1];
                a2 += v.z*whh[4*k+2]; a3 += v.w*whh[4*k+3];
            }
            float hn = fmaxf((a0+a1)+(a2+a3)+bias, 0.f);
            if (lane < NH) {
                hbuf[lane] = hn;
                if (t < sl) h_rev[sl-1-t][lane] = hn;
            }
        }
    }
    __syncthreads();

    const int o = 50 * wave + lane;
    float wzr[NZ]; float bz = 0.f;
    if (wave == 0 && lane < NH) {
        const float4* pp = reinterpret_cast<const float4*>(W_zh + lane * NZ);
#pragma unroll
        for (int k = 0; k < NZ / 4; ++k) {
            float4 v = pp[k];
            wzr[4*k+0]=v.x; wzr[4*k+1]=v.y; wzr[4*k+2]=v.z; wzr[4*k+3]=v.w;
        }
        bz = b_zh[lane];
    } else {
#pragma unroll
        for (int k = 0; k < NZ; ++k) wzr[k] = 0.f;
    }
    float wl[NH], ws_[NH]; float bl = 0.f, bs = 0.f;
    if (lane < 50) {
        const float4* pp = reinterpret_cast<const float4*>(W_hl + o * NH);
        const float4* q  = reinterpret_cast<const float4*>(W_hs + o * NH);
#pragma unroll
        for (int k = 0; k < NH / 4; ++k) {
            float4 v = pp[k];
            wl[4*k+0]=v.x; wl[4*k+1]=v.y; wl[4*k+2]=v.z; wl[4*k+3]=v.w;
            float4 u = q[k];
            ws_[4*k+0]=u.x; ws_[4*k+1]=u.y; ws_[4*k+2]=u.z; ws_[4*k+3]=u.w;
        }
        bl = b_hl[o]; bs = b_hs[o];
        zbuf[o] = zq0[o];
    } else {
#pragma unroll
        for (int k = 0; k < NH; ++k) { wl[k]=0.f; ws_[k]=0.f; }
    }
    __syncthreads();

    float* out_z = out;
    float* out_l = out + (size_t)NB * NT * NZ;
    float* out_s = out + (size_t)2 * NB * NT * NZ;
    const float* epsb = eps + (size_t)b * NZ;
    float e_cur = (lane < 50) ? epsb[o] : 0.f;

    for (int t = 0; t < NT; ++t) {
        if (wave == 0) {
            float a0=0.f,a1=0.f,a2=0.f,a3=0.f;
            const float4* z4 = reinterpret_cast<const float4*>(zbuf);
#pragma unroll
            for (int k = 0; k < NZ / 4; ++k) {
                float4 v = z4[k];
                a0 += v.x*wzr[4*k+0]; a1 += v.y*wzr[4*k+1];
                a2 += v.z*wzr[4*k+2]; a3 += v.w*wzr[4*k+3];
            }
            if (lane < NH) {
                float a = (a0+a1)+(a2+a3)+bz;
                hcomb[lane] = 0.5f * (fast_tanh(a) + h_rev[t][lane]);
            }
        }
        block_sync_lds();
        float e_nxt = 0.f;
        if (t + 1 < NT && lane < 50) e_nxt = epsb[(size_t)(t+1)*NB*NZ + o];
        if (lane < 50) {
            float c0=0.f,c1=0.f,c2=0.f,c3=0.f, d0=0.f,d1=0.f,d2=0.f,d3=0.f;
            const float4* h4 = reinterpret_cast<const float4*>(hcomb);
#pragma unroll
            for (int k = 0; k < NH / 4; ++k) {
                float4 v = h4[k];
                c0 += v.x*wl[4*k+0];  c1 += v.y*wl[4*k+1];
                c2 += v.z*wl[4*k+2];  c3 += v.w*wl[4*k+3];
                d0 += v.x*ws_[4*k+0]; d1 += v.y*ws_[4*k+1];
                d2 += v.z*ws_[4*k+2]; d3 += v.w*ws_[4*k+3];
            }
            float loc = (c0+c1)+(c2+c3)+bl;
            float ps  = (d0+d1)+(d2+d3)+bs;
            float sc  = fast_softplus(ps);
            float zv  = loc + sc * e_cur;
            size_t oi = ((size_t)b * NT + t) * NZ + o;
            out_z[oi]=zv; out_l[oi]=loc; out_s[oi]=sc;
            zbuf[o]=zv;
        }
        e_cur = e_nxt;
        block_sync_lds();
    }
}

extern "C" void kernel_launch(void* const* d_in, const int* in_sizes, int n_in,
                              void* d_out, int out_size, void* d_ws, size_t ws_size,
                              hipStream_t stream) {
    const float* xrev   = (const float*)d_in[1];
    const int*   seqlen = (const int*)  d_in[3];
    const float* eps    = (const float*)d_in[4];
    const float* W_ih   = (const float*)d_in[5];
    const float* W_hh   = (const float*)d_in[6];
    const float* b_ih   = (const float*)d_in[7];
    const float* b_hh   = (const float*)d_in[8];
    const float* h0     = (const float*)d_in[9];
    const float* zq0    = (const float*)d_in[10];
    const float* W_zh   = (const float*)d_in[11];
    const float* b_zh   = (const float*)d_in[12];
    const float* W_hl   = (const float*)d_in[13];
    const float* b_hl   = (const float*)d_in[14];
    const float* W_hs   = (const float*)d_in[15];
    const float* b_hs   = (const float*)d_in[16];
    float* out = (float*)d_out;

    const size_t pre_bytes = (size_t)NB * NT * NH * sizeof(float);
    if (ws_size >= pre_bytes) {
        float* pre = (float*)d_ws;
        pre_kernel<<<NB, 256, 0, stream>>>(xrev, W_ih, b_ih, b_hh, pre);
        fused128<<<NB, 128, 0, stream>>>(seqlen, eps, W_hh, h0, zq0,
                                         W_zh, b_zh, W_hl, b_hl, W_hs, b_hs,
                                         pre, out);
    } else {
        encoder_mono<<<NB, 128, 0, stream>>>(xrev, seqlen, eps,
                                             W_ih, W_hh, b_ih, b_hh, h0, zq0,
                                             W_zh, b_zh, W_hl, b_hl, W_hs, b_hs,
                                             out);
    }
}

// Round 8
// 342.556 us; speedup vs baseline: 2.5826x; 1.5038x over previous
//
#include <hip/hip_runtime.h>
#include <cmath>

#define NB 512
#define NT 200
#define NIN 88
#define NH 60
#define NZ 100

typedef float f2 __attribute__((ext_vector_type(2)));

__device__ __forceinline__ f2 pk_fma(f2 a, f2 b, f2 c) {
    return __builtin_elementwise_fma(a, b, c);
}
__device__ __forceinline__ float fast_tanh(float x) {
    float cx = fminf(fmaxf(x, -10.f), 10.f);
    float e  = __expf(2.f * cx);
    return (e - 1.f) * __builtin_amdgcn_rcpf(e + 1.f);
}
__device__ __forceinline__ float fast_softplus(float x) {
    return fmaxf(x, 0.f) + __logf(1.f + __expf(-fabsf(x)));
}
// LDS-only barrier (no vmcnt drain); global ops ride across, waited at use.
__device__ __forceinline__ void block_sync_lds() {
    asm volatile("s_waitcnt lgkmcnt(0)" ::: "memory");
    __builtin_amdgcn_s_barrier();
    asm volatile("" ::: "memory");
}

// ---------------------------------------------------------------------------
// Kernel 1: pre[b][t][h] = x_rev[b][t].W_ih[h] + b_ih[h] + b_hh[h]
// One wave per (b, t-chunk): weights in registers (loaded once), x staged via
// per-wave LDS (in-order, no barriers), 1-ahead register prefetch, no int div.
// Grid: (NB, 5); 128 threads = 2 waves; wave w handles t = w, w+2, ... (20 t).
// ---------------------------------------------------------------------------
#define TCHUNKS 5
#define TCL (NT / TCHUNKS)   // 40

__global__ __launch_bounds__(128, 1)
void pre_kernel(const float* __restrict__ xrev, const float* __restrict__ W_ih,
                const float* __restrict__ b_ih, const float* __restrict__ b_hh,
                float* __restrict__ pre)
{
    __shared__ __align__(16) float xw[2][NIN];   // per-wave staging (row=352B)

    const int b    = blockIdx.x;
    const int tc   = blockIdx.y;
    const int wv   = threadIdx.x >> 6;
    const int lane = threadIdx.x & 63;

    f2 wih2[44];
    float bias = 0.f;
    if (lane < NH) {
        const float4* p = reinterpret_cast<const float4*>(W_ih + lane * NIN);
#pragma unroll
        for (int k = 0; k < 22; ++k) {
            float4 v = p[k];
            wih2[2*k]   = f2{v.x, v.y};
            wih2[2*k+1] = f2{v.z, v.w};
        }
        bias = b_ih[lane] + b_hh[lane];
    } else {
#pragma unroll
        for (int k = 0; k < 44; ++k) wih2[k] = f2{0.f, 0.f};
    }

    const float* xb = xrev + ((size_t)b * NT + (size_t)tc * TCL) * NIN;
    float* pb = pre + ((size_t)b * NT + (size_t)tc * TCL) * NH;

    // prefetch x for this wave's first t
    float xa = xb[(size_t)wv * NIN + lane];
    float xc = (lane < NIN - 64) ? xb[(size_t)wv * NIN + 64 + lane] : 0.f;

    for (int k = 0; k < TCL / 2; ++k) {
        const int t = wv + 2 * k;
        xw[wv][lane] = xa;
        if (lane < NIN - 64) xw[wv][64 + lane] = xc;
        const int tn = t + 2;
        if (tn < TCL) {
            xa = xb[(size_t)tn * NIN + lane];
            xc = (lane < NIN - 64) ? xb[(size_t)tn * NIN + 64 + lane] : 0.f;
        }
        // in-order LDS: reads below see this wave's writes above
        const float4* x4 = reinterpret_cast<const float4*>(xw[wv]);
        f2 a0 = f2{bias, 0.f}, a1 = f2{0.f, 0.f};
#pragma unroll
        for (int q = 0; q < 22; ++q) {
            float4 v = x4[q];
            a0 = pk_fma(f2{v.x, v.y}, wih2[2*q],   a0);
            a1 = pk_fma(f2{v.z, v.w}, wih2[2*q+1], a1);
        }
        if (lane < NH) pb[(size_t)t * NH + lane] = (a0.x + a1.x) + (a0.y + a1.y);
    }
}

// ---------------------------------------------------------------------------
// Kernel 2: fused encoder. 128 threads = 2 waves (the only shape that reaches
// 2 blocks/CU -> all 512 blocks co-resident).
// Phase A: wave0 serial recurrence via pre (30 pk-fma/step, intra-wave LDS).
// Phase B: 1 barrier/step; both waves redundantly compute z-dot -> hcomb
// (per-wave LDS exchange, no barrier); lane l<50 of wave w owns output
// o=50w+l (0.5 pre-folded into W_hl/W_hs register copies); zbuf
// double-buffered (read zb[t&1], write zb[t&1^1]).
// ---------------------------------------------------------------------------
__global__ __launch_bounds__(128, 1)
void fused128(const int*   __restrict__ seqlen, // [B]
              const float* __restrict__ eps,    // [T][B][Z]
              const float* __restrict__ W_hh,   // [H][H]
              const float* __restrict__ h0,
              const float* __restrict__ zq0,
              const float* __restrict__ W_zh,   // [H][Z]
              const float* __restrict__ b_zh,
              const float* __restrict__ W_hl,   // [Z][H]
              const float* __restrict__ b_hl,
              const float* __restrict__ W_hs,   // [Z][H]
              const float* __restrict__ b_hs,
              const float* __restrict__ pre,    // [B][T][H] (ws)
              float* __restrict__ out)          // 3 x [B][T][Z]
{
    __shared__ __align__(16) float h_rev[NT][NH];     // 48000 B
    __shared__ __align__(16) float hbuf[NH + 4];
    __shared__ __align__(16) float zb[2][NZ + 4];     // double-buffered z
    __shared__ __align__(16) float hcw[2][NH + 4];    // per-wave hcomb

    const int b    = blockIdx.x;
    const int tid  = threadIdx.x;
    const int wv   = tid >> 6;
    const int lane = tid & 63;
    const int sl   = seqlen[b];

    // zero only the padded tail rows [sl, NT)
    {
        const int tail = (NT - sl) * NH;
        float* base = &h_rev[0][0] + sl * NH;
        for (int i = tid; i < tail; i += 128) base[i] = 0.0f;
    }

    f2 wzh2[50];      // wave0 phase A: [0:30]=W_hh row; phase B: W_zh row
    f2 wl2[30];       // lane<50: 0.5*W_hl[o]
    f2 ws2[30];       // lane<50: 0.5*W_hs[o]
    float bz = 0.f, bl = 0.f, bs = 0.f;
    const int  o   = 50 * wv + lane;      // valid when lane<50
    const bool oln = (lane < 50);
    float e_cur = 0.f;

    // ---- prologue: per-role loads ----
    if (oln) {
        const float4* p = reinterpret_cast<const float4*>(W_hl + o * NH);
        const float4* q = reinterpret_cast<const float4*>(W_hs + o * NH);
#pragma unroll
        for (int k = 0; k < 15; ++k) {
            float4 v = p[k];
            wl2[2*k]   = f2{0.5f * v.x, 0.5f * v.y};
            wl2[2*k+1] = f2{0.5f * v.z, 0.5f * v.w};
            float4 u = q[k];
            ws2[2*k]   = f2{0.5f * u.x, 0.5f * u.y};
            ws2[2*k+1] = f2{0.5f * u.z, 0.5f * u.w};
        }
        bl = b_hl[o];
        bs = b_hs[o];
        e_cur = eps[(size_t)b * NZ + o];          // eps[0][b][o]
        zb[0][o] = zq0[o];
    } else {
#pragma unroll
        for (int k = 0; k < 30; ++k) { wl2[k] = f2{0.f, 0.f}; ws2[k] = f2{0.f, 0.f}; }
    }

    if (wv == 0) {
        if (lane < NH) {
            const float4* q = reinterpret_cast<const float4*>(W_hh + lane * NH);
#pragma unroll
            for (int k = 0; k < 15; ++k) {
                float4 v = q[k];
                wzh2[2*k]   = f2{v.x, v.y};
                wzh2[2*k+1] = f2{v.z, v.w};
            }
#pragma unroll
            for (int k = 30; k < 50; ++k) wzh2[k] = f2{0.f, 0.f};
            hbuf[lane] = h0[lane];
        } else {
#pragma unroll
            for (int k = 0; k < 50; ++k) wzh2[k] = f2{0.f, 0.f};
        }
    } else {
        if (lane < NH) {
            const float4* q = reinterpret_cast<const float4*>(W_zh + lane * NZ);
#pragma unroll
            for (int k = 0; k < 25; ++k) {
                float4 v = q[k];
                wzh2[2*k]   = f2{v.x, v.y};
                wzh2[2*k+1] = f2{v.z, v.w};
            }
            bz = b_zh[lane];
        } else {
#pragma unroll
            for (int k = 0; k < 50; ++k) wzh2[k] = f2{0.f, 0.f};
        }
    }
    __syncthreads();   // h_rev tail + zb[0] + hbuf init visible

    // ---------------- Phase A: serial RNN (wave0 only, no barriers) ---------
    if (wv == 0) {
        const float* pb = pre + (size_t)b * NT * NH;
        float pcur = (lane < NH) ? pb[lane] : 0.f;
        for (int t = 0; t < NT; ++t) {
            float pnxt = (t + 1 < NT && lane < NH) ? pb[(size_t)(t+1)*NH + lane] : 0.f;
            const float4* h4 = reinterpret_cast<const float4*>(hbuf);
            f2 a0 = f2{pcur, 0.f}, a1 = f2{0.f, 0.f};
#pragma unroll
            for (int k = 0; k < 15; ++k) {
                float4 v = h4[k];
                a0 = pk_fma(f2{v.x, v.y}, wzh2[2*k],   a0);
                a1 = pk_fma(f2{v.z, v.w}, wzh2[2*k+1], a1);
            }
            float hn = fmaxf((a0.x + a1.x) + (a0.y + a1.y), 0.f);
            if (lane < NH) {
                hbuf[lane] = hn;                  // single-wave in-order LDS
                if (t < sl) h_rev[sl - 1 - t][lane] = hn;
            }
            pcur = pnxt;
        }
        // overlay reload: W_zh row for phase B
        if (lane < NH) {
            const float4* q = reinterpret_cast<const float4*>(W_zh + lane * NZ);
#pragma unroll
            for (int k = 0; k < 25; ++k) {
                float4 v = q[k];
                wzh2[2*k]   = f2{v.x, v.y};
                wzh2[2*k+1] = f2{v.z, v.w};
            }
            bz = b_zh[lane];
        } else {
#pragma unroll
            for (int k = 0; k < 50; ++k) wzh2[k] = f2{0.f, 0.f};
        }
    }
    block_sync_lds();   // h_rev complete, zb[0] ready

    // ---------------- Phase B: combiner, 1 barrier/step ----------------
    float* out_z = out;
    float* out_l = out + (size_t)NB * NT * NZ;
    float* out_s = out + (size_t)2 * NB * NT * NZ;

    for (int t = 0; t < NT; ++t) {
        const int r = t & 1;

        // h_rev row for this step (LDS, independent of z-dot -> overlaps)
        float hrow = (lane < NH) ? h_rev[t][lane] : 0.f;

        // z-dot: zb[r] broadcast reads x W_zh row (both waves, redundant)
        const float4* z4 = reinterpret_cast<const float4*>(zb[r]);
        f2 a0 = f2{0.f, 0.f}, a1 = f2{0.f, 0.f}, a2 = f2{0.f, 0.f}, a3 = f2{0.f, 0.f};
#pragma unroll
        for (int k = 0; k < 12; ++k) {
            float4 v = z4[k];
            a0 = pk_fma(f2{v.x, v.y}, wzh2[2*k],   a0);
            a1 = pk_fma(f2{v.z, v.w}, wzh2[2*k+1], a1);
        }
#pragma unroll
        for (int k = 12; k < 25; ++k) {
            float4 v = z4[k];
            a2 = pk_fma(f2{v.x, v.y}, wzh2[2*k],   a2);
            a3 = pk_fma(f2{v.z, v.w}, wzh2[2*k+1], a3);
        }

        // eps prefetch for next step (rides across the barrier)
        float e_nxt = (oln && t + 1 < NT)
                      ? eps[((size_t)(t + 1) * NB + b) * NZ + o] : 0.f;

        if (lane < NH) {
            f2 s2 = (a0 + a1) + (a2 + a3);
            float a = s2.x + s2.y + bz;
            hcw[wv][lane] = fast_tanh(a) + hrow;   // 0.5 folded into wl2/ws2
        }

        // intra-wave read-back of this wave's hcomb (in-order, no barrier)
        const float4* h4 = reinterpret_cast<const float4*>(hcw[wv]);
        f2 l0 = f2{0.f, 0.f}, l1 = f2{0.f, 0.f};
        f2 s0 = f2{0.f, 0.f}, s1 = f2{0.f, 0.f};
#pragma unroll
        for (int k = 0; k < 15; ++k) {
            float4 v = h4[k];
            f2 lo = f2{v.x, v.y}, hi = f2{v.z, v.w};
            l0 = pk_fma(lo, wl2[2*k],   l0);
            l1 = pk_fma(hi, wl2[2*k+1], l1);
            s0 = pk_fma(lo, ws2[2*k],   s0);
            s1 = pk_fma(hi, ws2[2*k+1], s1);
        }
        if (oln) {
            f2 lv = l0 + l1, sv = s0 + s1;
            float loc = (lv.x + lv.y) + bl;
            float ps  = (sv.x + sv.y) + bs;
            float sc  = fast_softplus(ps);
            float zv  = loc + sc * e_cur;
            size_t oi = ((size_t)b * NT + t) * NZ + o;
            out_z[oi] = zv;
            out_l[oi] = loc;
            out_s[oi] = sc;
            zb[r ^ 1][o] = zv;        // write the OTHER buffer (race-free)
            e_cur = e_nxt;
        }
        block_sync_lds();             // zb[r^1] visible; zb[r] reads done
    }
}

// ---------------------------------------------------------------------------
// Fallback (ws too small): proven monolithic kernel (no workspace).
// ---------------------------------------------------------------------------
__global__ __launch_bounds__(128, 1)
void encoder_mono(const float* __restrict__ xrev, const int* __restrict__ seqlen,
                  const float* __restrict__ eps,
                  const float* __restrict__ W_ih, const float* __restrict__ W_hh,
                  const float* __restrict__ b_ih, const float* __restrict__ b_hh,
                  const float* __restrict__ h0,   const float* __restrict__ zq0,
                  const float* __restrict__ W_zh, const float* __restrict__ b_zh,
                  const float* __restrict__ W_hl, const float* __restrict__ b_hl,
                  const float* __restrict__ W_hs, const float* __restrict__ b_hs,
                  float* __restrict__ out)
{
    __shared__ __align__(16) float h_rev[NT][NH];
    __shared__ __align__(16) float xbuf[NIN];
    __shared__ __align__(16) float hbuf[NH];
    __shared__ __align__(16) float zbuf[NZ];
    __shared__ __align__(16) float hcomb[NH];

    const int b = blockIdx.x, tid = threadIdx.x;
    const int wave = tid >> 6, lane = tid & 63;
    const int sl = seqlen[b];

    for (int i = tid; i < NT * NH; i += 128) (&h_rev[0][0])[i] = 0.0f;
    __syncthreads();

    if (wave == 0) {
        float wih[NIN], whh[NH];
        float bias = 0.f;
        if (lane < NH) {
            const float4* pp = reinterpret_cast<const float4*>(W_ih + lane * NIN);
#pragma unroll
            for (int k = 0; k < NIN / 4; ++k) {
                float4 v = pp[k];
                wih[4*k+0]=v.x; wih[4*k+1]=v.y; wih[4*k+2]=v.z; wih[4*k+3]=v.w;
            }
            const float4* q = reinterpret_cast<const float4*>(W_hh + lane * NH);
#pragma unroll
            for (int k = 0; k < NH / 4; ++k) {
                float4 v = q[k];
                whh[4*k+0]=v.x; whh[4*k+1]=v.y; whh[4*k+2]=v.z; whh[4*k+3]=v.w;
            }
            bias = b_ih[lane] + b_hh[lane];
            hbuf[lane] = h0[lane];
        } else {
#pragma unroll
            for (int k = 0; k < NIN; ++k) wih[k] = 0.f;
#pragma unroll
            for (int k = 0; k < NH; ++k) whh[k] = 0.f;
        }
        const float* xb = xrev + (size_t)b * NT * NIN;
        float xa = xb[lane];
        float xc = (lane < NIN - 64) ? xb[64 + lane] : 0.f;
        for (int t = 0; t < NT; ++t) {
            xbuf[lane] = xa;
            if (lane < NIN - 64) xbuf[64 + lane] = xc;
            if (t + 1 < NT) {
                xa = xb[(size_t)(t+1)*NIN + lane];
                xc = (lane < NIN - 64) ? xb[(size_t)(t+1)*NIN + 64 + lane] : 0.f;
            }
            float a0=0.f,a1=0.f,a2=0.f,a3=0.f;
            const float4* x4 = reinterpret_cast<const float4*>(xbuf);
#pragma unroll
            for (int k = 0; k < NIN / 4; ++k) {
                float4 v = x4[k];
                a0 += v.x*wih[4*k+0]; a1 += v.y*wih[4*k+1];
                a2 += v.z*wih[4*k+2]; a3 += v.w*wih[4*k+3];
            }
            const float4* h4 = reinterpret_cast<const float4*>(hbuf);
#pragma unroll
            for (int k = 0; k < NH / 4; ++k) {
                float4 v = h4[k];
                a0 += v.x*whh[4*k+0]; a1 += v.y*whh[4*k+1];
                a2 += v.z*whh[4*k+2]; a3 += v.w*whh[4*k+3];
            }
            float hn = fmaxf((a0+a1)+(a2+a3)+bias, 0.f);
            if (lane < NH) {
                hbuf[lane] = hn;
                if (t < sl) h_rev[sl-1-t][lane] = hn;
            }
        }
    }
    __syncthreads();

    const int o = 50 * wave + lane;
    float wzr[NZ]; float bz = 0.f;
    if (wave == 0 && lane < NH) {
        const float4* pp = reinterpret_cast<const float4*>(W_zh + lane * NZ);
#pragma unroll
        for (int k = 0; k < NZ / 4; ++k) {
            float4 v = pp[k];
            wzr[4*k+0]=v.x; wzr[4*k+1]=v.y; wzr[4*k+2]=v.z; wzr[4*k+3]=v.w;
        }
        bz = b_zh[lane];
    } else {
#pragma unroll
        for (int k = 0; k < NZ; ++k) wzr[k] = 0.f;
    }
    float wl[NH], ws_[NH]; float bl = 0.f, bs = 0.f;
    if (lane < 50) {
        const float4* pp = reinterpret_cast<const float4*>(W_hl + o * NH);
        const float4* q  = reinterpret_cast<const float4*>(W_hs + o * NH);
#pragma unroll
        for (int k = 0; k < NH / 4; ++k) {
            float4 v = pp[k];
            wl[4*k+0]=v.x; wl[4*k+1]=v.y; wl[4*k+2]=v.z; wl[4*k+3]=v.w;
            float4 u = q[k];
            ws_[4*k+0]=u.x; ws_[4*k+1]=u.y; ws_[4*k+2]=u.z; ws_[4*k+3]=u.w;
        }
        bl = b_hl[o]; bs = b_hs[o];
        zbuf[o] = zq0[o];
    } else {
#pragma unroll
        for (int k = 0; k < NH; ++k) { wl[k]=0.f; ws_[k]=0.f; }
    }
    __syncthreads();

    float* out_z = out;
    float* out_l = out + (size_t)NB * NT * NZ;
    float* out_s = out + (size_t)2 * NB * NT * NZ;
    const float* epsb = eps + (size_t)b * NZ;
    float e_cur = (lane < 50) ? epsb[o] : 0.f;

    for (int t = 0; t < NT; ++t) {
        if (wave == 0) {
            float a0=0.f,a1=0.f,a2=0.f,a3=0.f;
            const float4* z4 = reinterpret_cast<const float4*>(zbuf);
#pragma unroll
            for (int k = 0; k < NZ / 4; ++k) {
                float4 v = z4[k];
                a0 += v.x*wzr[4*k+0]; a1 += v.y*wzr[4*k+1];
                a2 += v.z*wzr[4*k+2]; a3 += v.w*wzr[4*k+3];
            }
            if (lane < NH) {
                float a = (a0+a1)+(a2+a3)+bz;
                hcomb[lane] = 0.5f * (fast_tanh(a) + h_rev[t][lane]);
            }
        }
        block_sync_lds();
        float e_nxt = 0.f;
        if (t + 1 < NT && lane < 50) e_nxt = epsb[(size_t)(t+1)*NB*NZ + o];
        if (lane < 50) {
            float c0=0.f,c1=0.f,c2=0.f,c3=0.f, d0=0.f,d1=0.f,d2=0.f,d3=0.f;
            const float4* h4 = reinterpret_cast<const float4*>(hcomb);
#pragma unroll
            for (int k = 0; k < NH / 4; ++k) {
                float4 v = h4[k];
                c0 += v.x*wl[4*k+0];  c1 += v.y*wl[4*k+1];
                c2 += v.z*wl[4*k+2];  c3 += v.w*wl[4*k+3];
                d0 += v.x*ws_[4*k+0]; d1 += v.y*ws_[4*k+1];
                d2 += v.z*ws_[4*k+2]; d3 += v.w*ws_[4*k+3];
            }
            float loc = (c0+c1)+(c2+c3)+bl;
            float ps  = (d0+d1)+(d2+d3)+bs;
            float sc  = fast_softplus(ps);
            float zv  = loc + sc * e_cur;
            size_t oi = ((size_t)b * NT + t) * NZ + o;
            out_z[oi]=zv; out_l[oi]=loc; out_s[oi]=sc;
            zbuf[o]=zv;
        }
        e_cur = e_nxt;
        block_sync_lds();
    }
}

extern "C" void kernel_launch(void* const* d_in, const int* in_sizes, int n_in,
                              void* d_out, int out_size, void* d_ws, size_t ws_size,
                              hipStream_t stream) {
    const float* xrev   = (const float*)d_in[1];
    const int*   seqlen = (const int*)  d_in[3];
    const float* eps    = (const float*)d_in[4];
    const float* W_ih   = (const float*)d_in[5];
    const float* W_hh   = (const float*)d_in[6];
    const float* b_ih   = (const float*)d_in[7];
    const float* b_hh   = (const float*)d_in[8];
    const float* h0     = (const float*)d_in[9];
    const float* zq0    = (const float*)d_in[10];
    const float* W_zh   = (const float*)d_in[11];
    const float* b_zh   = (const float*)d_in[12];
    const float* W_hl   = (const float*)d_in[13];
    const float* b_hl   = (const float*)d_in[14];
    const float* W_hs   = (const float*)d_in[15];
    const float* b_hs   = (const float*)d_in[16];
    float* out = (float*)d_out;

    const size_t pre_bytes = (size_t)NB * NT * NH * sizeof(float);
    if (ws_size >= pre_bytes) {
        float* pre = (float*)d_ws;
        pre_kernel<<<dim3(NB, TCHUNKS), 128, 0, stream>>>(xrev, W_ih, b_ih, b_hh, pre);
        fused128<<<NB, 128, 0, stream>>>(seqlen, eps, W_hh, h0, zq0,
                                         W_zh, b_zh, W_hl, b_hl, W_hs, b_hs,
                                         pre, out);
    } else {
        encoder_mono<<<NB, 128, 0, stream>>>(xrev, seqlen, eps,
                                             W_ih, W_hh, b_ih, b_hh, h0, zq0,
                                             W_zh, b_zh, W_hl, b_hl, W_hs, b_hs,
                                             out);
    }
}

// Round 9
// 311.782 us; speedup vs baseline: 2.8375x; 1.0987x over previous
//
#include <hip/hip_runtime.h>
#include <cmath>

#define NB 512
#define NT 200
#define NIN 88
#define NH 60
#define NZ 100

typedef float f2 __attribute__((ext_vector_type(2)));
typedef _Float16 h2v __attribute__((ext_vector_type(2)));
typedef _Float16 h8v __attribute__((ext_vector_type(8)));

__device__ __forceinline__ f2 pk_fma(f2 a, f2 b, f2 c) {
    return __builtin_elementwise_fma(a, b, c);
}
__device__ __forceinline__ float dot2(h2v a, h2v b, float c) {
#if __has_builtin(__builtin_amdgcn_fdot2)
    return __builtin_amdgcn_fdot2(a, b, c, false);
#else
    return fmaf((float)a.x, (float)b.x, fmaf((float)a.y, (float)b.y, c));
#endif
}
__device__ __forceinline__ float fast_tanh(float x) {
    float cx = fminf(fmaxf(x, -10.f), 10.f);
    float e  = __expf(2.f * cx);
    return (e - 1.f) * __builtin_amdgcn_rcpf(e + 1.f);
}
__device__ __forceinline__ float fast_softplus(float x) {
    return fmaxf(x, 0.f) + __logf(1.f + __expf(-fabsf(x)));
}
// LDS-only barrier (no vmcnt drain); global ops ride across, waited at use.
__device__ __forceinline__ void block_sync_lds() {
    asm volatile("s_waitcnt lgkmcnt(0)" ::: "memory");
    __builtin_amdgcn_s_barrier();
    asm volatile("" ::: "memory");
}

// ---------------------------------------------------------------------------
// Kernel 1: pre[b][t][h] = x_rev[b][t].W_ih[h] + b_ih[h] + b_hh[h]
// One wave per (b, t-chunk); weights in registers, x via per-wave LDS.
// ---------------------------------------------------------------------------
#define TCHUNKS 5
#define TCL (NT / TCHUNKS)   // 40

__global__ __launch_bounds__(128, 1)
void pre_kernel(const float* __restrict__ xrev, const float* __restrict__ W_ih,
                const float* __restrict__ b_ih, const float* __restrict__ b_hh,
                float* __restrict__ pre)
{
    __shared__ __align__(16) float xw[2][NIN];

    const int b    = blockIdx.x;
    const int tc   = blockIdx.y;
    const int wv   = threadIdx.x >> 6;
    const int lane = threadIdx.x & 63;

    f2 wih2[44];
    float bias = 0.f;
    if (lane < NH) {
        const float4* p = reinterpret_cast<const float4*>(W_ih + lane * NIN);
#pragma unroll
        for (int k = 0; k < 22; ++k) {
            float4 v = p[k];
            wih2[2*k]   = f2{v.x, v.y};
            wih2[2*k+1] = f2{v.z, v.w};
        }
        bias = b_ih[lane] + b_hh[lane];
    } else {
#pragma unroll
        for (int k = 0; k < 44; ++k) wih2[k] = f2{0.f, 0.f};
    }

    const float* xb = xrev + ((size_t)b * NT + (size_t)tc * TCL) * NIN;
    float* pb = pre + ((size_t)b * NT + (size_t)tc * TCL) * NH;

    float xa = xb[(size_t)wv * NIN + lane];
    float xc = (lane < NIN - 64) ? xb[(size_t)wv * NIN + 64 + lane] : 0.f;

    for (int k = 0; k < TCL / 2; ++k) {
        const int t = wv + 2 * k;
        xw[wv][lane] = xa;
        if (lane < NIN - 64) xw[wv][64 + lane] = xc;
        const int tn = t + 2;
        if (tn < TCL) {
            xa = xb[(size_t)tn * NIN + lane];
            xc = (lane < NIN - 64) ? xb[(size_t)tn * NIN + 64 + lane] : 0.f;
        }
        const float4* x4 = reinterpret_cast<const float4*>(xw[wv]);
        f2 a0 = f2{bias, 0.f}, a1 = f2{0.f, 0.f};
#pragma unroll
        for (int q = 0; q < 22; ++q) {
            float4 v = x4[q];
            a0 = pk_fma(f2{v.x, v.y}, wih2[2*q],   a0);
            a1 = pk_fma(f2{v.z, v.w}, wih2[2*q+1], a1);
        }
        if (lane < NH) pb[(size_t)t * NH + lane] = (a0.x + a1.x) + (a0.y + a1.y);
    }
}

// ---------------------------------------------------------------------------
// Kernel 2: fused encoder. 128 threads = 2 waves (2 blocks/CU -> all 512
// blocks co-resident). Phase A: wave0 serial recurrence (f32, 4-deep pre
// prefetch). Phase B: 1 barrier/step; f16 weights + f16 LDS broadcasts via
// v_dot2_f32_f16 -> per-lane register demand ~150 (NO spill; r8's 172-count
// vs ~240 demand put scratch reloads on the serial chain every step).
// ---------------------------------------------------------------------------
__global__ __launch_bounds__(128, 1)
void fused128(const int*   __restrict__ seqlen, // [B]
              const float* __restrict__ eps,    // [T][B][Z]
              const float* __restrict__ W_hh,   // [H][H]
              const float* __restrict__ h0,
              const float* __restrict__ zq0,
              const float* __restrict__ W_zh,   // [H][Z]
              const float* __restrict__ b_zh,
              const float* __restrict__ W_hl,   // [Z][H]
              const float* __restrict__ b_hl,
              const float* __restrict__ W_hs,   // [Z][H]
              const float* __restrict__ b_hs,
              const float* __restrict__ pre,    // [B][T][H] (ws)
              float* __restrict__ out)          // 3 x [B][T][Z]
{
    __shared__ __align__(16) float    h_rev[NT][NH];   // 48000 B
    __shared__ __align__(16) float    hbuf[NH + 4];
    __shared__ __align__(16) _Float16 zbh[2][112];     // z as f16, 224B rows
    __shared__ __align__(16) _Float16 hch[2][64];      // per-wave hcomb (f16)

    const int b    = blockIdx.x;
    const int tid  = threadIdx.x;
    const int wv   = tid >> 6;
    const int lane = tid & 63;
    const int sl   = seqlen[b];

    // zero padded tail rows of h_rev
    {
        const int tail = (NT - sl) * NH;
        float* base = &h_rev[0][0] + sl * NH;
        for (int i = tid; i < tail; i += 128) base[i] = 0.0f;
    }
    // zero the f16 pads (read by the padded h8 dot loops)
    if (tid < 12) { zbh[0][100 + tid] = (_Float16)0; zbh[1][100 + tid] = (_Float16)0; }
    if (lane >= NH) hch[wv][lane] = (_Float16)0;

    f2  whh2[30];     // phase A only (wave0): f32 W_hh row
    h2v wzh_h[52];    // phase B: f16 W_zh row (pads zero)
    h2v wl_h[32];     // f16 0.5*W_hl[o] (pads zero)
    h2v ws_h[32];     // f16 0.5*W_hs[o]
    float bz = 0.f, bl = 0.f, bs = 0.f;
    const int  o   = 50 * wv + lane;
    const bool oln = (lane < 50);
    float e_cur = 0.f;

    // ---- prologue ----
    if (oln) {
        const float4* p = reinterpret_cast<const float4*>(W_hl + o * NH);
        const float4* q = reinterpret_cast<const float4*>(W_hs + o * NH);
#pragma unroll
        for (int k = 0; k < 15; ++k) {
            float4 v = p[k];
            wl_h[2*k]   = h2v{(_Float16)(0.5f * v.x), (_Float16)(0.5f * v.y)};
            wl_h[2*k+1] = h2v{(_Float16)(0.5f * v.z), (_Float16)(0.5f * v.w)};
            float4 u = q[k];
            ws_h[2*k]   = h2v{(_Float16)(0.5f * u.x), (_Float16)(0.5f * u.y)};
            ws_h[2*k+1] = h2v{(_Float16)(0.5f * u.z), (_Float16)(0.5f * u.w)};
        }
        wl_h[30] = h2v{(_Float16)0, (_Float16)0}; wl_h[31] = wl_h[30];
        ws_h[30] = wl_h[30]; ws_h[31] = wl_h[30];
        bl = b_hl[o];
        bs = b_hs[o];
        e_cur = eps[(size_t)b * NZ + o];
        zbh[0][o] = (_Float16)zq0[o];
    } else {
#pragma unroll
        for (int k = 0; k < 32; ++k) { wl_h[k] = h2v{(_Float16)0, (_Float16)0}; ws_h[k] = wl_h[k]; }
    }

    if (wv == 0) {
        if (lane < NH) {
            const float4* q = reinterpret_cast<const float4*>(W_hh + lane * NH);
#pragma unroll
            for (int k = 0; k < 15; ++k) {
                float4 v = q[k];
                whh2[2*k]   = f2{v.x, v.y};
                whh2[2*k+1] = f2{v.z, v.w};
            }
            hbuf[lane] = h0[lane];
        } else {
#pragma unroll
            for (int k = 0; k < 30; ++k) whh2[k] = f2{0.f, 0.f};
        }
    } else {
        // wave1 loads its f16 W_zh row now (it would otherwise idle in phase A)
        if (lane < NH) {
            const float4* q = reinterpret_cast<const float4*>(W_zh + lane * NZ);
#pragma unroll
            for (int k = 0; k < 25; ++k) {
                float4 v = q[k];
                wzh_h[2*k]   = h2v{(_Float16)v.x, (_Float16)v.y};
                wzh_h[2*k+1] = h2v{(_Float16)v.z, (_Float16)v.w};
            }
            bz = b_zh[lane];
        } else {
#pragma unroll
            for (int k = 0; k < 50; ++k) wzh_h[k] = h2v{(_Float16)0, (_Float16)0};
        }
        wzh_h[50] = h2v{(_Float16)0, (_Float16)0};
        wzh_h[51] = wzh_h[50];
    }
    __syncthreads();

    // ---------------- Phase A: serial RNN (wave0, no barriers) ----------
    if (wv == 0) {
        const float* pb = pre + (size_t)b * NT * NH;
        const bool hl = (lane < NH);
        float p0 = hl ? pb[0 * NH + lane] : 0.f;
        float p1 = hl ? pb[1 * NH + lane] : 0.f;
        float p2 = hl ? pb[2 * NH + lane] : 0.f;
        float p3 = hl ? pb[3 * NH + lane] : 0.f;
        for (int t = 0; t < NT; ++t) {
            float pn = (t + 4 < NT && hl) ? pb[(size_t)(t + 4) * NH + lane] : 0.f;
            const float4* h4 = reinterpret_cast<const float4*>(hbuf);
            f2 a0 = f2{p0, 0.f}, a1 = f2{0.f, 0.f};
#pragma unroll
            for (int k = 0; k < 15; ++k) {
                float4 v = h4[k];
                a0 = pk_fma(f2{v.x, v.y}, whh2[2*k],   a0);
                a1 = pk_fma(f2{v.z, v.w}, whh2[2*k+1], a1);
            }
            float hn = fmaxf((a0.x + a1.x) + (a0.y + a1.y), 0.f);
            if (hl) {
                hbuf[lane] = hn;                  // single-wave in-order LDS
                if (t < sl) h_rev[sl - 1 - t][lane] = hn;
            }
            p0 = p1; p1 = p2; p2 = p3; p3 = pn;
        }
        // load f16 W_zh row for phase B (whh2 dead from here)
        if (lane < NH) {
            const float4* q = reinterpret_cast<const float4*>(W_zh + lane * NZ);
#pragma unroll
            for (int k = 0; k < 25; ++k) {
                float4 v = q[k];
                wzh_h[2*k]   = h2v{(_Float16)v.x, (_Float16)v.y};
                wzh_h[2*k+1] = h2v{(_Float16)v.z, (_Float16)v.w};
            }
            bz = b_zh[lane];
        } else {
#pragma unroll
            for (int k = 0; k < 50; ++k) wzh_h[k] = h2v{(_Float16)0, (_Float16)0};
        }
        wzh_h[50] = h2v{(_Float16)0, (_Float16)0};
        wzh_h[51] = wzh_h[50];
    }
    block_sync_lds();   // h_rev complete, zbh[0] ready

    // ---------------- Phase B: combiner, 1 barrier/step ----------------
    float* out_z = out;
    float* out_l = out + (size_t)NB * NT * NZ;
    float* out_s = out + (size_t)2 * NB * NT * NZ;

    for (int t = 0; t < NT; ++t) {
        const int r = t & 1;

        float hrow = (lane < NH) ? h_rev[t][lane] : 0.f;

        // z-dot over f16 z (broadcast reads) x f16 W_zh row
        const h8v* z8 = reinterpret_cast<const h8v*>(&zbh[r][0]);
        float za0 = 0.f, za1 = 0.f, za2 = 0.f, za3 = 0.f;
#pragma unroll
        for (int k = 0; k < 13; ++k) {
            h8v v = z8[k];
            za0 = dot2(h2v{v[0], v[1]}, wzh_h[4*k+0], za0);
            za1 = dot2(h2v{v[2], v[3]}, wzh_h[4*k+1], za1);
            za2 = dot2(h2v{v[4], v[5]}, wzh_h[4*k+2], za2);
            za3 = dot2(h2v{v[6], v[7]}, wzh_h[4*k+3], za3);
        }

        // eps prefetch for next step (rides across the barrier)
        float e_nxt = (oln && t + 1 < NT)
                      ? eps[((size_t)(t + 1) * NB + b) * NZ + o] : 0.f;

        if (lane < NH) {
            float a = (za0 + za1) + (za2 + za3) + bz;
            hch[wv][lane] = (_Float16)(fast_tanh(a) + hrow);  // 0.5 in wl/ws
        }

        // intra-wave read-back of this wave's hcomb (in-order, no barrier)
        const h8v* h8p = reinterpret_cast<const h8v*>(&hch[wv][0]);
        float l0 = 0.f, l1 = 0.f, l2 = 0.f, l3 = 0.f;
        float s0 = 0.f, s1 = 0.f, s2 = 0.f, s3 = 0.f;
#pragma unroll
        for (int k = 0; k < 8; ++k) {
            h8v v = h8p[k];
            h2v x0 = h2v{v[0], v[1]}, x1 = h2v{v[2], v[3]};
            h2v x2 = h2v{v[4], v[5]}, x3 = h2v{v[6], v[7]};
            l0 = dot2(x0, wl_h[4*k+0], l0);
            l1 = dot2(x1, wl_h[4*k+1], l1);
            l2 = dot2(x2, wl_h[4*k+2], l2);
            l3 = dot2(x3, wl_h[4*k+3], l3);
            s0 = dot2(x0, ws_h[4*k+0], s0);
            s1 = dot2(x1, ws_h[4*k+1], s1);
            s2 = dot2(x2, ws_h[4*k+2], s2);
            s3 = dot2(x3, ws_h[4*k+3], s3);
        }
        if (oln) {
            float loc = (l0 + l1) + (l2 + l3) + bl;
            float ps  = (s0 + s1) + (s2 + s3) + bs;
            float sc  = fast_softplus(ps);
            float zv  = loc + sc * e_cur;
            size_t oi = ((size_t)b * NT + t) * NZ + o;
            out_z[oi] = zv;
            out_l[oi] = loc;
            out_s[oi] = sc;
            zbh[r ^ 1][o] = (_Float16)zv;   // other buffer (race-free)
            e_cur = e_nxt;
        }
        block_sync_lds();                   // zbh[r^1] visible
    }
}

// ---------------------------------------------------------------------------
// Fallback (ws too small): proven monolithic kernel.
// ---------------------------------------------------------------------------
__global__ __launch_bounds__(128, 1)
void encoder_mono(const float* __restrict__ xrev, const int* __restrict__ seqlen,
                  const float* __restrict__ eps,
                  const float* __restrict__ W_ih, const float* __restrict__ W_hh,
                  const float* __restrict__ b_ih, const float* __restrict__ b_hh,
                  const float* __restrict__ h0,   const float* __restrict__ zq0,
                  const float* __restrict__ W_zh, const float* __restrict__ b_zh,
                  const float* __restrict__ W_hl, const float* __restrict__ b_hl,
                  const float* __restrict__ W_hs, const float* __restrict__ b_hs,
                  float* __restrict__ out)
{
    __shared__ __align__(16) float h_rev[NT][NH];
    __shared__ __align__(16) float xbuf[NIN];
    __shared__ __align__(16) float hbuf[NH];
    __shared__ __align__(16) float zbuf[NZ];
    __shared__ __align__(16) float hcomb[NH];

    const int b = blockIdx.x, tid = threadIdx.x;
    const int wave = tid >> 6, lane = tid & 63;
    const int sl = seqlen[b];

    for (int i = tid; i < NT * NH; i += 128) (&h_rev[0][0])[i] = 0.0f;
    __syncthreads();

    if (wave == 0) {
        float wih[NIN], whh[NH];
        float bias = 0.f;
        if (lane < NH) {
            const float4* pp = reinterpret_cast<const float4*>(W_ih + lane * NIN);
#pragma unroll
            for (int k = 0; k < NIN / 4; ++k) {
                float4 v = pp[k];
                wih[4*k+0]=v.x; wih[4*k+1]=v.y; wih[4*k+2]=v.z; wih[4*k+3]=v.w;
            }
            const float4* q = reinterpret_cast<const float4*>(W_hh + lane * NH);
#pragma unroll
            for (int k = 0; k < NH / 4; ++k) {
                float4 v = q[k];
                whh[4*k+0]=v.x; whh[4*k+1]=v.y; whh[4*k+2]=v.z; whh[4*k+3]=v.w;
            }
            bias = b_ih[lane] + b_hh[lane];
            hbuf[lane] = h0[lane];
        } else {
#pragma unroll
            for (int k = 0; k < NIN; ++k) wih[k] = 0.f;
#pragma unroll
            for (int k = 0; k < NH; ++k) whh[k] = 0.f;
        }
        const float* xb = xrev + (size_t)b * NT * NIN;
        float xa = xb[lane];
        float xc = (lane < NIN - 64) ? xb[64 + lane] : 0.f;
        for (int t = 0; t < NT; ++t) {
            xbuf[lane] = xa;
            if (lane < NIN - 64) xbuf[64 + lane] = xc;
            if (t + 1 < NT) {
                xa = xb[(size_t)(t+1)*NIN + lane];
                xc = (lane < NIN - 64) ? xb[(size_t)(t+1)*NIN + 64 + lane] : 0.f;
            }
            float a0=0.f,a1=0.f,a2=0.f,a3=0.f;
            const float4* x4 = reinterpret_cast<const float4*>(xbuf);
#pragma unroll
            for (int k = 0; k < NIN / 4; ++k) {
                float4 v = x4[k];
                a0 += v.x*wih[4*k+0]; a1 += v.y*wih[4*k+1];
                a2 += v.z*wih[4*k+2]; a3 += v.w*wih[4*k+3];
            }
            const float4* h4 = reinterpret_cast<const float4*>(hbuf);
#pragma unroll
            for (int k = 0; k < NH / 4; ++k) {
                float4 v = h4[k];
                a0 += v.x*whh[4*k+0]; a1 += v.y*whh[4*k+1];
                a2 += v.z*whh[4*k+2]; a3 += v.w*whh[4*k+3];
            }
            float hn = fmaxf((a0+a1)+(a2+a3)+bias, 0.f);
            if (lane < NH) {
                hbuf[lane] = hn;
                if (t < sl) h_rev[sl-1-t][lane] = hn;
            }
        }
    }
    __syncthreads();

    const int o = 50 * wave + lane;
    float wzr[NZ]; float bz = 0.f;
    if (wave == 0 && lane < NH) {
        const float4* pp = reinterpret_cast<const float4*>(W_zh + lane * NZ);
#pragma unroll
        for (int k = 0; k < NZ / 4; ++k) {
            float4 v = pp[k];
            wzr[4*k+0]=v.x; wzr[4*k+1]=v.y; wzr[4*k+2]=v.z; wzr[4*k+3]=v.w;
        }
        bz = b_zh[lane];
    } else {
#pragma unroll
        for (int k = 0; k < NZ; ++k) wzr[k] = 0.f;
    }
    float wl[NH], ws_[NH]; float bl = 0.f, bs = 0.f;
    if (lane < 50) {
        const float4* pp = reinterpret_cast<const float4*>(W_hl + o * NH);
        const float4* q  = reinterpret_cast<const float4*>(W_hs + o * NH);
#pragma unroll
        for (int k = 0; k < NH / 4; ++k) {
            float4 v = pp[k];
            wl[4*k+0]=v.x; wl[4*k+1]=v.y; wl[4*k+2]=v.z; wl[4*k+3]=v.w;
            float4 u = q[k];
            ws_[4*k+0]=u.x; ws_[4*k+1]=u.y; ws_[4*k+2]=u.z; ws_[4*k+3]=u.w;
        }
        bl = b_hl[o]; bs = b_hs[o];
        zbuf[o] = zq0[o];
    } else {
#pragma unroll
        for (int k = 0; k < NH; ++k) { wl[k]=0.f; ws_[k]=0.f; }
    }
    __syncthreads();

    float* out_z = out;
    float* out_l = out + (size_t)NB * NT * NZ;
    float* out_s = out + (size_t)2 * NB * NT * NZ;
    const float* epsb = eps + (size_t)b * NZ;
    float e_cur = (lane < 50) ? epsb[o] : 0.f;

    for (int t = 0; t < NT; ++t) {
        if (wave == 0) {
            float a0=0.f,a1=0.f,a2=0.f,a3=0.f;
            const float4* z4 = reinterpret_cast<const float4*>(zbuf);
#pragma unroll
            for (int k = 0; k < NZ / 4; ++k) {
                float4 v = z4[k];
                a0 += v.x*wzr[4*k+0]; a1 += v.y*wzr[4*k+1];
                a2 += v.z*wzr[4*k+2]; a3 += v.w*wzr[4*k+3];
            }
            if (lane < NH) {
                float a = (a0+a1)+(a2+a3)+bz;
                hcomb[lane] = 0.5f * (fast_tanh(a) + h_rev[t][lane]);
            }
        }
        block_sync_lds();
        float e_nxt = 0.f;
        if (t + 1 < NT && lane < 50) e_nxt = epsb[(size_t)(t+1)*NB*NZ + o];
        if (lane < 50) {
            float c0=0.f,c1=0.f,c2=0.f,c3=0.f, d0=0.f,d1=0.f,d2=0.f,d3=0.f;
            const float4* h4 = reinterpret_cast<const float4*>(hcomb);
#pragma unroll
            for (int k = 0; k < NH / 4; ++k) {
                float4 v = h4[k];
                c0 += v.x*wl[4*k+0];  c1 += v.y*wl[4*k+1];
                c2 += v.z*wl[4*k+2];  c3 += v.w*wl[4*k+3];
                d0 += v.x*ws_[4*k+0]; d1 += v.y*ws_[4*k+1];
                d2 += v.z*ws_[4*k+2]; d3 += v.w*ws_[4*k+3];
            }
            float loc = (c0+c1)+(c2+c3)+bl;
            float ps  = (d0+d1)+(d2+d3)+bs;
            float sc  = fast_softplus(ps);
            float zv  = loc + sc * e_cur;
            size_t oi = ((size_t)b * NT + t) * NZ + o;
            out_z[oi]=zv; out_l[oi]=loc; out_s[oi]=sc;
            zbuf[o]=zv;
        }
        e_cur = e_nxt;
        block_sync_lds();
    }
}

extern "C" void kernel_launch(void* const* d_in, const int* in_sizes, int n_in,
                              void* d_out, int out_size, void* d_ws, size_t ws_size,
                              hipStream_t stream) {
    const float* xrev   = (const float*)d_in[1];
    const int*   seqlen = (const int*)  d_in[3];
    const float* eps    = (const float*)d_in[4];
    const float* W_ih   = (const float*)d_in[5];
    const float* W_hh   = (const float*)d_in[6];
    const float* b_ih   = (const float*)d_in[7];
    const float* b_hh   = (const float*)d_in[8];
    const float* h0     = (const float*)d_in[9];
    const float* zq0    = (const float*)d_in[10];
    const float* W_zh   = (const float*)d_in[11];
    const float* b_zh   = (const float*)d_in[12];
    const float* W_hl   = (const float*)d_in[13];
    const float* b_hl   = (const float*)d_in[14];
    const float* W_hs   = (const float*)d_in[15];
    const float* b_hs   = (const float*)d_in[16];
    float* out = (float*)d_out;

    const size_t pre_bytes = (size_t)NB * NT * NH * sizeof(float);
    if (ws_size >= pre_bytes) {
        float* pre = (float*)d_ws;
        pre_kernel<<<dim3(NB, TCHUNKS), 128, 0, stream>>>(xrev, W_ih, b_ih, b_hh, pre);
        fused128<<<NB, 128, 0, stream>>>(seqlen, eps, W_hh, h0, zq0,
                                         W_zh, b_zh, W_hl, b_hl, W_hs, b_hs,
                                         pre, out);
    } else {
        encoder_mono<<<NB, 128, 0, stream>>>(xrev, seqlen, eps,
                                             W_ih, W_hh, b_ih, b_hh, h0, zq0,
                                             W_zh, b_zh, W_hl, b_hl, W_hs, b_hs,
                                             out);
    }
}

// Round 10
// 276.187 us; speedup vs baseline: 3.2032x; 1.1289x over previous
//
#include <hip/hip_runtime.h>
#include <cmath>

#define NB 512
#define NT 200
#define NIN 88
#define NH 60
#define NZ 100

typedef float f2 __attribute__((ext_vector_type(2)));
typedef _Float16 h2v __attribute__((ext_vector_type(2)));
typedef _Float16 h8v __attribute__((ext_vector_type(8)));

__device__ __forceinline__ f2 pk_fma(f2 a, f2 b, f2 c) {
    return __builtin_elementwise_fma(a, b, c);
}
__device__ __forceinline__ float dot2(h2v a, h2v b, float c) {
#if __has_builtin(__builtin_amdgcn_fdot2)
    return __builtin_amdgcn_fdot2(a, b, c, false);
#else
    return fmaf((float)a.x, (float)b.x, fmaf((float)a.y, (float)b.y, c));
#endif
}
__device__ __forceinline__ float fast_tanh(float x) {
    float cx = fminf(fmaxf(x, -10.f), 10.f);
    float e  = __expf(2.f * cx);
    return (e - 1.f) * __builtin_amdgcn_rcpf(e + 1.f);
}
__device__ __forceinline__ float fast_softplus(float x) {
    return fmaxf(x, 0.f) + __logf(1.f + __expf(-fabsf(x)));
}
// LDS-only barrier (used by fallback kernel only)
__device__ __forceinline__ void block_sync_lds() {
    asm volatile("s_waitcnt lgkmcnt(0)" ::: "memory");
    __builtin_amdgcn_s_barrier();
    asm volatile("" ::: "memory");
}

// ---------------------------------------------------------------------------
// Kernel 1: pre[b][t][h] = x_rev[b][t].W_ih[h] + b_ih[h] + b_hh[h]
// ---------------------------------------------------------------------------
#define TCHUNKS 5
#define TCL (NT / TCHUNKS)   // 40

__global__ __launch_bounds__(128, 1)
void pre_kernel(const float* __restrict__ xrev, const float* __restrict__ W_ih,
                const float* __restrict__ b_ih, const float* __restrict__ b_hh,
                float* __restrict__ pre)
{
    __shared__ __align__(16) float xw[2][NIN];

    const int b    = blockIdx.x;
    const int tc   = blockIdx.y;
    const int wv   = threadIdx.x >> 6;
    const int lane = threadIdx.x & 63;

    f2 wih2[44];
    float bias = 0.f;
    if (lane < NH) {
        const float4* p = reinterpret_cast<const float4*>(W_ih + lane * NIN);
#pragma unroll
        for (int k = 0; k < 22; ++k) {
            float4 v = p[k];
            wih2[2*k]   = f2{v.x, v.y};
            wih2[2*k+1] = f2{v.z, v.w};
        }
        bias = b_ih[lane] + b_hh[lane];
    } else {
#pragma unroll
        for (int k = 0; k < 44; ++k) wih2[k] = f2{0.f, 0.f};
    }

    const float* xb = xrev + ((size_t)b * NT + (size_t)tc * TCL) * NIN;
    float* pb = pre + ((size_t)b * NT + (size_t)tc * TCL) * NH;

    float xa = xb[(size_t)wv * NIN + lane];
    float xc = (lane < NIN - 64) ? xb[(size_t)wv * NIN + 64 + lane] : 0.f;

    for (int k = 0; k < TCL / 2; ++k) {
        const int t = wv + 2 * k;
        xw[wv][lane] = xa;
        if (lane < NIN - 64) xw[wv][64 + lane] = xc;
        const int tn = t + 2;
        if (tn < TCL) {
            xa = xb[(size_t)tn * NIN + lane];
            xc = (lane < NIN - 64) ? xb[(size_t)tn * NIN + 64 + lane] : 0.f;
        }
        const float4* x4 = reinterpret_cast<const float4*>(xw[wv]);
        f2 a0 = f2{bias, 0.f}, a1 = f2{0.f, 0.f};
#pragma unroll
        for (int q = 0; q < 22; ++q) {
            float4 v = x4[q];
            a0 = pk_fma(f2{v.x, v.y}, wih2[2*q],   a0);
            a1 = pk_fma(f2{v.z, v.w}, wih2[2*q+1], a1);
        }
        if (lane < NH) pb[(size_t)t * NH + lane] = (a0.x + a1.x) + (a0.y + a1.y);
    }
}

// ---------------------------------------------------------------------------
// Kernel 2: fused encoder, ONE WAVE PER SEQUENCE, ZERO BARRIERS.
// 128-thr blocks (proven 2-blocks/CU shape) carry 2 independent sequences;
// all h/hcomb/z exchange is intra-wave LDS (in-order, no sync needed).
// Phase A: serial recurrence h=relu(pre[t]+h@W_hh.T) (f32), h_rev stored f16.
// Phase B per step (one wave): z-dot (lane<60, f16 dot2) -> tanh+h_rev ->
// hch write/readback (intra-wave) -> lane<50 computes BOTH outputs o, o+50
// (4 f16 weight rows in regs) -> stores + z feedback into zbh (intra-wave).
// ---------------------------------------------------------------------------
__global__ __launch_bounds__(128, 1)
void fused1w(const int*   __restrict__ seqlen, // [B]
             const float* __restrict__ eps,    // [T][B][Z]
             const float* __restrict__ W_hh,   // [H][H]
             const float* __restrict__ h0,
             const float* __restrict__ zq0,
             const float* __restrict__ W_zh,   // [H][Z]
             const float* __restrict__ b_zh,
             const float* __restrict__ W_hl,   // [Z][H]
             const float* __restrict__ b_hl,
             const float* __restrict__ W_hs,   // [Z][H]
             const float* __restrict__ b_hs,
             const float* __restrict__ pre,    // [B][T][H] (ws)
             float* __restrict__ out)          // 3 x [B][T][Z]
{
    __shared__ __align__(16) _Float16 h_rev_h[2][NT][NH];  // 2 x 24000 B
    __shared__ __align__(16) float    hbuf[2][64];
    __shared__ __align__(16) _Float16 zbh[2][112];
    __shared__ __align__(16) _Float16 hch[2][64];

    const int wv   = threadIdx.x >> 6;
    const int lane = threadIdx.x & 63;
    const int b    = blockIdx.x * 2 + wv;     // this wave's sequence
    const int sl   = seqlen[b];

    // zero this sequence's padded tail rows [sl, NT) (f16)
    {
        const int tail = (NT - sl) * NH;
        _Float16* base = &h_rev_h[wv][sl][0];
        for (int i = lane; i < tail; i += 64) base[i] = (_Float16)0;
    }
    // pads
    if (lane < 12) zbh[wv][100 + lane] = (_Float16)0;
    if (lane >= NH) hch[wv][lane] = (_Float16)0;

    const bool oln = (lane < 50);
    const int  o1  = lane;          // first owned output (lane<50)
    const int  o2  = lane + 50;     // second owned output
    float e1 = 0.f, e2 = 0.f;
    if (oln) {
        zbh[wv][o1] = (_Float16)zq0[o1];
        zbh[wv][o2] = (_Float16)zq0[o2];
        e1 = eps[(size_t)b * NZ + o1];
        e2 = eps[(size_t)b * NZ + o2];
    }

    // ---------------- Phase A: serial RNN (per-wave, no barriers) -----------
    {
        f2 whh2[30];
        if (lane < NH) {
            const float4* q = reinterpret_cast<const float4*>(W_hh + lane * NH);
#pragma unroll
            for (int k = 0; k < 15; ++k) {
                float4 v = q[k];
                whh2[2*k]   = f2{v.x, v.y};
                whh2[2*k+1] = f2{v.z, v.w};
            }
            hbuf[wv][lane] = h0[lane];
        } else {
#pragma unroll
            for (int k = 0; k < 30; ++k) whh2[k] = f2{0.f, 0.f};
        }

        const float* pb = pre + (size_t)b * NT * NH;
        const bool hl = (lane < NH);
        float p0 = hl ? pb[0 * NH + lane] : 0.f;
        float p1 = hl ? pb[1 * NH + lane] : 0.f;
        float p2 = hl ? pb[2 * NH + lane] : 0.f;
        float p3 = hl ? pb[3 * NH + lane] : 0.f;
        for (int t = 0; t < NT; ++t) {
            float pn = (t + 4 < NT && hl) ? pb[(size_t)(t + 4) * NH + lane] : 0.f;
            const float4* h4 = reinterpret_cast<const float4*>(&hbuf[wv][0]);
            f2 a0 = f2{p0, 0.f}, a1 = f2{0.f, 0.f};
#pragma unroll
            for (int k = 0; k < 15; ++k) {
                float4 v = h4[k];
                a0 = pk_fma(f2{v.x, v.y}, whh2[2*k],   a0);
                a1 = pk_fma(f2{v.z, v.w}, whh2[2*k+1], a1);
            }
            float hn = fmaxf((a0.x + a1.x) + (a0.y + a1.y), 0.f);
            if (hl) {
                hbuf[wv][lane] = hn;                 // intra-wave in-order LDS
                if (t < sl) h_rev_h[wv][sl - 1 - t][lane] = (_Float16)hn;
            }
            p0 = p1; p1 = p2; p2 = p3; p3 = pn;
        }
    }

    // ---- load phase-B weights (after phase A: liveness doesn't overlap) ----
    h2v wzh_h[52];
    float bz = 0.f;
    if (lane < NH) {
        const float4* q = reinterpret_cast<const float4*>(W_zh + lane * NZ);
#pragma unroll
        for (int k = 0; k < 25; ++k) {
            float4 v = q[k];
            wzh_h[2*k]   = h2v{(_Float16)v.x, (_Float16)v.y};
            wzh_h[2*k+1] = h2v{(_Float16)v.z, (_Float16)v.w};
        }
        bz = b_zh[lane];
    } else {
#pragma unroll
        for (int k = 0; k < 50; ++k) wzh_h[k] = h2v{(_Float16)0, (_Float16)0};
    }
    wzh_h[50] = h2v{(_Float16)0, (_Float16)0};
    wzh_h[51] = wzh_h[50];

    h2v wlA[32], wsA[32], wlB[32], wsB[32];   // 0.5-folded f16 rows for o1,o2
    float blA = 0.f, bsA = 0.f, blB = 0.f, bsB = 0.f;
    if (oln) {
        const float4* pA = reinterpret_cast<const float4*>(W_hl + o1 * NH);
        const float4* qA = reinterpret_cast<const float4*>(W_hs + o1 * NH);
        const float4* pB = reinterpret_cast<const float4*>(W_hl + o2 * NH);
        const float4* qB = reinterpret_cast<const float4*>(W_hs + o2 * NH);
#pragma unroll
        for (int k = 0; k < 15; ++k) {
            float4 v;
            v = pA[k];
            wlA[2*k]   = h2v{(_Float16)(0.5f*v.x), (_Float16)(0.5f*v.y)};
            wlA[2*k+1] = h2v{(_Float16)(0.5f*v.z), (_Float16)(0.5f*v.w)};
            v = qA[k];
            wsA[2*k]   = h2v{(_Float16)(0.5f*v.x), (_Float16)(0.5f*v.y)};
            wsA[2*k+1] = h2v{(_Float16)(0.5f*v.z), (_Float16)(0.5f*v.w)};
            v = pB[k];
            wlB[2*k]   = h2v{(_Float16)(0.5f*v.x), (_Float16)(0.5f*v.y)};
            wlB[2*k+1] = h2v{(_Float16)(0.5f*v.z), (_Float16)(0.5f*v.w)};
            v = qB[k];
            wsB[2*k]   = h2v{(_Float16)(0.5f*v.x), (_Float16)(0.5f*v.y)};
            wsB[2*k+1] = h2v{(_Float16)(0.5f*v.z), (_Float16)(0.5f*v.w)};
        }
        blA = b_hl[o1]; bsA = b_hs[o1];
        blB = b_hl[o2]; bsB = b_hs[o2];
    } else {
#pragma unroll
        for (int k = 0; k < 32; ++k) {
            wlA[k] = h2v{(_Float16)0, (_Float16)0};
            wsA[k] = wlA[k]; wlB[k] = wlA[k]; wsB[k] = wlA[k];
        }
    }
    h2v zpad = h2v{(_Float16)0, (_Float16)0};
    wlA[30] = zpad; wlA[31] = zpad; wsA[30] = zpad; wsA[31] = zpad;
    wlB[30] = zpad; wlB[31] = zpad; wsB[30] = zpad; wsB[31] = zpad;

    // ---------------- Phase B: combiner (per-wave, no barriers) -------------
    float* out_z = out;
    float* out_l = out + (size_t)NB * NT * NZ;
    float* out_s = out + (size_t)2 * NB * NT * NZ;

    for (int t = 0; t < NT; ++t) {
        // z-dot over this wave's own zbh (written by same wave last step)
        const h8v* z8 = reinterpret_cast<const h8v*>(&zbh[wv][0]);
        float za0 = 0.f, za1 = 0.f, za2 = 0.f, za3 = 0.f;
#pragma unroll
        for (int k = 0; k < 13; ++k) {
            h8v v = z8[k];
            za0 = dot2(h2v{v[0], v[1]}, wzh_h[4*k+0], za0);
            za1 = dot2(h2v{v[2], v[3]}, wzh_h[4*k+1], za1);
            za2 = dot2(h2v{v[4], v[5]}, wzh_h[4*k+2], za2);
            za3 = dot2(h2v{v[6], v[7]}, wzh_h[4*k+3], za3);
        }
        float hrow = (lane < NH) ? (float)h_rev_h[wv][t][lane] : 0.f;

        // eps prefetch for next step
        float e1n = 0.f, e2n = 0.f;
        if (oln && t + 1 < NT) {
            const float* ep = eps + ((size_t)(t + 1) * NB + b) * NZ;
            e1n = ep[o1];
            e2n = ep[o2];
        }

        if (lane < NH) {
            float a = (za0 + za1) + (za2 + za3) + bz;
            hch[wv][lane] = (_Float16)(fast_tanh(a) + hrow);  // 0.5 in weights
        }

        // intra-wave readback of hcomb (in-order LDS, no barrier)
        const h8v* h8p = reinterpret_cast<const h8v*>(&hch[wv][0]);
        float lA0 = 0.f, lA1 = 0.f, sA0 = 0.f, sA1 = 0.f;
        float lB0 = 0.f, lB1 = 0.f, sB0 = 0.f, sB1 = 0.f;
#pragma unroll
        for (int k = 0; k < 8; ++k) {
            h8v v = h8p[k];
            h2v x0 = h2v{v[0], v[1]}, x1 = h2v{v[2], v[3]};
            h2v x2 = h2v{v[4], v[5]}, x3 = h2v{v[6], v[7]};
            lA0 = dot2(x0, wlA[4*k+0], lA0);
            lA1 = dot2(x1, wlA[4*k+1], lA1);
            lA0 = dot2(x2, wlA[4*k+2], lA0);
            lA1 = dot2(x3, wlA[4*k+3], lA1);
            sA0 = dot2(x0, wsA[4*k+0], sA0);
            sA1 = dot2(x1, wsA[4*k+1], sA1);
            sA0 = dot2(x2, wsA[4*k+2], sA0);
            sA1 = dot2(x3, wsA[4*k+3], sA1);
            lB0 = dot2(x0, wlB[4*k+0], lB0);
            lB1 = dot2(x1, wlB[4*k+1], lB1);
            lB0 = dot2(x2, wlB[4*k+2], lB0);
            lB1 = dot2(x3, wlB[4*k+3], lB1);
            sB0 = dot2(x0, wsB[4*k+0], sB0);
            sB1 = dot2(x1, wsB[4*k+1], sB1);
            sB0 = dot2(x2, wsB[4*k+2], sB0);
            sB1 = dot2(x3, wsB[4*k+3], sB1);
        }
        if (oln) {
            float locA = lA0 + lA1 + blA;
            float psA  = sA0 + sA1 + bsA;
            float scA  = fast_softplus(psA);
            float zA   = locA + scA * e1;
            float locB = lB0 + lB1 + blB;
            float psB  = sB0 + sB1 + bsB;
            float scB  = fast_softplus(psB);
            float zB   = locB + scB * e2;
            size_t oi = ((size_t)b * NT + t) * NZ;
            out_z[oi + o1] = zA;  out_z[oi + o2] = zB;
            out_l[oi + o1] = locA; out_l[oi + o2] = locB;
            out_s[oi + o1] = scA;  out_s[oi + o2] = scB;
            zbh[wv][o1] = (_Float16)zA;      // feedback: intra-wave in-order
            zbh[wv][o2] = (_Float16)zB;
            e1 = e1n; e2 = e2n;
        }
    }
}

// ---------------------------------------------------------------------------
// Fallback (ws too small): proven monolithic kernel.
// ---------------------------------------------------------------------------
__global__ __launch_bounds__(128, 1)
void encoder_mono(const float* __restrict__ xrev, const int* __restrict__ seqlen,
                  const float* __restrict__ eps,
                  const float* __restrict__ W_ih, const float* __restrict__ W_hh,
                  const float* __restrict__ b_ih, const float* __restrict__ b_hh,
                  const float* __restrict__ h0,   const float* __restrict__ zq0,
                  const float* __restrict__ W_zh, const float* __restrict__ b_zh,
                  const float* __restrict__ W_hl, const float* __restrict__ b_hl,
                  const float* __restrict__ W_hs, const float* __restrict__ b_hs,
                  float* __restrict__ out)
{
    __shared__ __align__(16) float h_rev[NT][NH];
    __shared__ __align__(16) float xbuf[NIN];
    __shared__ __align__(16) float hbuf[NH];
    __shared__ __align__(16) float zbuf[NZ];
    __shared__ __align__(16) float hcomb[NH];

    const int b = blockIdx.x, tid = threadIdx.x;
    const int wave = tid >> 6, lane = tid & 63;
    const int sl = seqlen[b];

    for (int i = tid; i < NT * NH; i += 128) (&h_rev[0][0])[i] = 0.0f;
    __syncthreads();

    if (wave == 0) {
        float wih[NIN], whh[NH];
        float bias = 0.f;
        if (lane < NH) {
            const float4* pp = reinterpret_cast<const float4*>(W_ih + lane * NIN);
#pragma unroll
            for (int k = 0; k < NIN / 4; ++k) {
                float4 v = pp[k];
                wih[4*k+0]=v.x; wih[4*k+1]=v.y; wih[4*k+2]=v.z; wih[4*k+3]=v.w;
            }
            const float4* q = reinterpret_cast<const float4*>(W_hh + lane * NH);
#pragma unroll
            for (int k = 0; k < NH / 4; ++k) {
                float4 v = q[k];
                whh[4*k+0]=v.x; whh[4*k+1]=v.y; whh[4*k+2]=v.z; whh[4*k+3]=v.w;
            }
            bias = b_ih[lane] + b_hh[lane];
            hbuf[lane] = h0[lane];
        } else {
#pragma unroll
            for (int k = 0; k < NIN; ++k) wih[k] = 0.f;
#pragma unroll
            for (int k = 0; k < NH; ++k) whh[k] = 0.f;
        }
        const float* xb = xrev + (size_t)b * NT * NIN;
        float xa = xb[lane];
        float xc = (lane < NIN - 64) ? xb[64 + lane] : 0.f;
        for (int t = 0; t < NT; ++t) {
            xbuf[lane] = xa;
            if (lane < NIN - 64) xbuf[64 + lane] = xc;
            if (t + 1 < NT) {
                xa = xb[(size_t)(t+1)*NIN + lane];
                xc = (lane < NIN - 64) ? xb[(size_t)(t+1)*NIN + 64 + lane] : 0.f;
            }
            float a0=0.f,a1=0.f,a2=0.f,a3=0.f;
            const float4* x4 = reinterpret_cast<const float4*>(xbuf);
#pragma unroll
            for (int k = 0; k < NIN / 4; ++k) {
                float4 v = x4[k];
                a0 += v.x*wih[4*k+0]; a1 += v.y*wih[4*k+1];
                a2 += v.z*wih[4*k+2]; a3 += v.w*wih[4*k+3];
            }
            const float4* h4 = reinterpret_cast<const float4*>(hbuf);
#pragma unroll
            for (int k = 0; k < NH / 4; ++k) {
                float4 v = h4[k];
                a0 += v.x*whh[4*k+0]; a1 += v.y*whh[4*k+1];
                a2 += v.z*whh[4*k+2]; a3 += v.w*whh[4*k+3];
            }
            float hn = fmaxf((a0+a1)+(a2+a3)+bias, 0.f);
            if (lane < NH) {
                hbuf[lane] = hn;
                if (t < sl) h_rev[sl-1-t][lane] = hn;
            }
        }
    }
    __syncthreads();

    const int o = 50 * wave + lane;
    float wzr[NZ]; float bz = 0.f;
    if (wave == 0 && lane < NH) {
        const float4* pp = reinterpret_cast<const float4*>(W_zh + lane * NZ);
#pragma unroll
        for (int k = 0; k < NZ / 4; ++k) {
            float4 v = pp[k];
            wzr[4*k+0]=v.x; wzr[4*k+1]=v.y; wzr[4*k+2]=v.z; wzr[4*k+3]=v.w;
        }
        bz = b_zh[lane];
    } else {
#pragma unroll
        for (int k = 0; k < NZ; ++k) wzr[k] = 0.f;
    }
    float wl[NH], ws_[NH]; float bl = 0.f, bs = 0.f;
    if (lane < 50) {
        const float4* pp = reinterpret_cast<const float4*>(W_hl + o * NH);
        const float4* q  = reinterpret_cast<const float4*>(W_hs + o * NH);
#pragma unroll
        for (int k = 0; k < NH / 4; ++k) {
            float4 v = pp[k];
            wl[4*k+0]=v.x; wl[4*k+1]=v.y; wl[4*k+2]=v.z; wl[4*k+3]=v.w;
            float4 u = q[k];
            ws_[4*k+0]=u.x; ws_[4*k+1]=u.y; ws_[4*k+2]=u.z; ws_[4*k+3]=u.w;
        }
        bl = b_hl[o]; bs = b_hs[o];
        zbuf[o] = zq0[o];
    } else {
#pragma unroll
        for (int k = 0; k < NH; ++k) { wl[k]=0.f; ws_[k]=0.f; }
    }
    __syncthreads();

    float* out_z = out;
    float* out_l = out + (size_t)NB * NT * NZ;
    float* out_s = out + (size_t)2 * NB * NT * NZ;
    const float* epsb = eps + (size_t)b * NZ;
    float e_cur = (lane < 50) ? epsb[o] : 0.f;

    for (int t = 0; t < NT; ++t) {
        if (wave == 0) {
            float a0=0.f,a1=0.f,a2=0.f,a3=0.f;
            const float4* z4 = reinterpret_cast<const float4*>(zbuf);
#pragma unroll
            for (int k = 0; k < NZ / 4; ++k) {
                float4 v = z4[k];
                a0 += v.x*wzr[4*k+0]; a1 += v.y*wzr[4*k+1];
                a2 += v.z*wzr[4*k+2]; a3 += v.w*wzr[4*k+3];
            }
            if (lane < NH) {
                float a = (a0+a1)+(a2+a3)+bz;
                hcomb[lane] = 0.5f * (fast_tanh(a) + h_rev[t][lane]);
            }
        }
        block_sync_lds();
        float e_nxt = 0.f;
        if (t + 1 < NT && lane < 50) e_nxt = epsb[(size_t)(t+1)*NB*NZ + o];
        if (lane < 50) {
            float c0=0.f,c1=0.f,c2=0.f,c3=0.f, d0=0.f,d1=0.f,d2=0.f,d3=0.f;
            const float4* h4 = reinterpret_cast<const float4*>(hcomb);
#pragma unroll
            for (int k = 0; k < NH / 4; ++k) {
                float4 v = h4[k];
                c0 += v.x*wl[4*k+0];  c1 += v.y*wl[4*k+1];
                c2 += v.z*wl[4*k+2];  c3 += v.w*wl[4*k+3];
                d0 += v.x*ws_[4*k+0]; d1 += v.y*ws_[4*k+1];
                d2 += v.z*ws_[4*k+2]; d3 += v.w*ws_[4*k+3];
            }
            float loc = (c0+c1)+(c2+c3)+bl;
            float ps  = (d0+d1)+(d2+d3)+bs;
            float sc  = fast_softplus(ps);
            float zv  = loc + sc * e_cur;
            size_t oi = ((size_t)b * NT + t) * NZ + o;
            out_z[oi]=zv; out_l[oi]=loc; out_s[oi]=sc;
            zbuf[o]=zv;
        }
        e_cur = e_nxt;
        block_sync_lds();
    }
}

extern "C" void kernel_launch(void* const* d_in, const int* in_sizes, int n_in,
                              void* d_out, int out_size, void* d_ws, size_t ws_size,
                              hipStream_t stream) {
    const float* xrev   = (const float*)d_in[1];
    const int*   seqlen = (const int*)  d_in[3];
    const float* eps    = (const float*)d_in[4];
    const float* W_ih   = (const float*)d_in[5];
    const float* W_hh   = (const float*)d_in[6];
    const float* b_ih   = (const float*)d_in[7];
    const float* b_hh   = (const float*)d_in[8];
    const float* h0     = (const float*)d_in[9];
    const float* zq0    = (const float*)d_in[10];
    const float* W_zh   = (const float*)d_in[11];
    const float* b_zh   = (const float*)d_in[12];
    const float* W_hl   = (const float*)d_in[13];
    const float* b_hl   = (const float*)d_in[14];
    const float* W_hs   = (const float*)d_in[15];
    const float* b_hs   = (const float*)d_in[16];
    float* out = (float*)d_out;

    const size_t pre_bytes = (size_t)NB * NT * NH * sizeof(float);
    if (ws_size >= pre_bytes) {
        float* pre = (float*)d_ws;
        pre_kernel<<<dim3(NB, TCHUNKS), 128, 0, stream>>>(xrev, W_ih, b_ih, b_hh, pre);
        fused1w<<<NB / 2, 128, 0, stream>>>(seqlen, eps, W_hh, h0, zq0,
                                            W_zh, b_zh, W_hl, b_hl, W_hs, b_hs,
                                            pre, out);
    } else {
        encoder_mono<<<NB, 128, 0, stream>>>(xrev, seqlen, eps,
                                             W_ih, W_hh, b_ih, b_hh, h0, zq0,
                                             W_zh, b_zh, W_hl, b_hl, W_hs, b_hs,
                                             out);
    }
}